// Round 12
// baseline (237.856 us; speedup 1.0000x reference)
//
#include <hip/hip_runtime.h>

#define N_NODES 50000
#define N_EDGES 800000
#define D 128
#define N_LABELS 4096
#define HB 256           // histogram blocks (3125 edges each, exact)
#define HWORDS 12500     // 50000/4 packed u8 counters per block (50 KB LDS)
#define EPB (N_EDGES / HB)     // 3125 edges per hist/fill block
#define PRESCALE_BLOCKS 6250   // N_NODES*32 float4 / 256
#define UVEC_BLOCKS 12500      // 4 nodes per block
#define FLAG_BLOCKS 16         // 4096 labels / 256
#define SCAN_BLOCKS 196
#define MMW_BLOCKS 8           // 128x128 matmul, 16 rows/block

// ---------------------------------------------------------------------------
// small dense helpers (fp32, no LDS, W L1/L2-resident)
// ---------------------------------------------------------------------------

#define MM16_STEP(kk, comp)                                           \
    {                                                                 \
        float4 w0 = W4[(size_t)(k4 + kk) * 32 + tx * 2];              \
        float4 w1 = W4[(size_t)(k4 + kk) * 32 + tx * 2 + 1];          \
        acc[0] = fmaf(a.comp, w0.x, acc[0]);                          \
        acc[1] = fmaf(a.comp, w0.y, acc[1]);                          \
        acc[2] = fmaf(a.comp, w0.z, acc[2]);                          \
        acc[3] = fmaf(a.comp, w0.w, acc[3]);                          \
        acc[4] = fmaf(a.comp, w1.x, acc[4]);                          \
        acc[5] = fmaf(a.comp, w1.y, acc[5]);                          \
        acc[6] = fmaf(a.comp, w1.z, acc[6]);                          \
        acc[7] = fmaf(a.comp, w1.w, acc[7]);                          \
    }

__device__ __forceinline__ void mm_tile16(const float* __restrict__ A,
                                          const float* __restrict__ W,
                                          float* __restrict__ C, int r0, int t) {
    int tx = t & 15, ty = t >> 4;
    int r = r0 + ty;
    const float4* A4 = (const float4*)A;
    const float4* W4 = (const float4*)W;
    float acc[8] = {0.f, 0.f, 0.f, 0.f, 0.f, 0.f, 0.f, 0.f};
#pragma unroll 4
    for (int kb = 0; kb < 32; ++kb) {
        float4 a = A4[(size_t)r * 32 + kb];
        int k4 = kb * 4;
        MM16_STEP(0, x)
        MM16_STEP(1, y)
        MM16_STEP(2, z)
        MM16_STEP(3, w)
    }
    float4* cp = (float4*)&C[(size_t)r * D + tx * 8];
    float4 o0, o1;
    o0.x = acc[0]; o0.y = acc[1]; o0.z = acc[2]; o0.w = acc[3];
    o1.x = acc[4]; o1.y = acc[5]; o1.z = acc[6]; o1.w = acc[7];
    cp[0] = o0;
    cp[1] = o1;
}

__device__ __forceinline__ void vecmat128(const float* __restrict__ v,
                                          const float* __restrict__ W,
                                          float* __restrict__ outp, int t) {
    if (t < D) {
        float acc = 0.f;
#pragma unroll 8
        for (int k = 0; k < D; ++k) acc = fmaf(v[k], W[(size_t)k * D + t], acc);
        outp[t] = acc;
    }
}

// ---------------------------------------------------------------------------
// K1: hetero {src LDS histogram | dst LDS histogram | W01 = W0@W1 | bv01 = b0@W1}
// no global atomics anywhere
// ---------------------------------------------------------------------------

__global__ __launch_bounds__(256) void hist2_w_kernel(
        const int* __restrict__ src, const int* __restrict__ dst,
        unsigned int* __restrict__ Hsrc, unsigned int* __restrict__ Hdst,
        const float* __restrict__ W0, const float* __restrict__ W1,
        const float* __restrict__ b0, float* __restrict__ W01,
        float* __restrict__ bv01) {
    __shared__ unsigned int hist[HWORDS];
    int t = threadIdx.x;
    if (blockIdx.x < 2 * HB) {
        int isDst = (blockIdx.x >= HB);
        int hb = isDst ? (blockIdx.x - HB) : blockIdx.x;
        const int* keys = isDst ? dst : src;
        unsigned int* Hout = isDst ? Hdst : Hsrc;
        for (int i = t; i < HWORDS; i += 256) hist[i] = 0;
        __syncthreads();
        int base = hb * EPB;
        int end = base + EPB;
        for (int e = base + t; e < end; e += 256) {
            int n = keys[e];
            atomicAdd(&hist[n >> 2], 1u << ((n & 3) * 8));
        }
        __syncthreads();
        unsigned int* outp = Hout + (size_t)hb * HWORDS;
        for (int i = t; i < HWORDS; i += 256) outp[i] = hist[i];
    } else if (blockIdx.x < 2 * HB + MMW_BLOCKS) {
        mm_tile16(W0, W1, W01, (blockIdx.x - 2 * HB) * 16, t);
    } else {
        vecmat128(b0, W1, bv01, t);
    }
}

// ---------------------------------------------------------------------------
// K2: hetero {src merge -> dinv_out | dst merge -> boff,cnt_in,dinv_in |
//             Wc = W01@W2 | bc1 = bv01@W2 | bc2 = b1@W2}
// ---------------------------------------------------------------------------

__global__ __launch_bounds__(256) void merge_w_kernel(
        const unsigned int* __restrict__ Hsrc, const unsigned int* __restrict__ Hdst,
        float* __restrict__ dinv_out, float* __restrict__ dinv_in,
        int* __restrict__ cnt_in, unsigned char* __restrict__ boff,
        const float* __restrict__ W01, const float* __restrict__ W2,
        const float* __restrict__ bv01, const float* __restrict__ b1,
        float* __restrict__ Wc, float* __restrict__ bc1, float* __restrict__ bc2) {
    int t = threadIdx.x;
    if (blockIdx.x < SCAN_BLOCKS) {
        int n = blockIdx.x * 256 + t;
        if (n >= N_NODES) return;
        int w = n >> 2, sh = (n & 3) * 8;
        unsigned int s = 0;
#pragma unroll 8
        for (int b = 0; b < HB; ++b) s += (Hsrc[(size_t)b * HWORDS + w] >> sh) & 0xFFu;
        dinv_out[n] = (s > 0) ? 1.0f / sqrtf((float)s) : 0.0f;
    } else if (blockIdx.x < 2 * SCAN_BLOCKS) {
        int n = (blockIdx.x - SCAN_BLOCKS) * 256 + t;
        if (n >= N_NODES) return;
        int w = n >> 2, sh = (n & 3) * 8;
        unsigned int run = 0;
        for (int b = 0; b < HB; ++b) {
            boff[(size_t)b * N_NODES + n] = (unsigned char)run;
            run += (Hdst[(size_t)b * HWORDS + w] >> sh) & 0xFFu;
        }
        cnt_in[n] = (int)run;
        dinv_in[n] = (run > 0) ? 1.0f / sqrtf((float)run) : 0.0f;
    } else if (blockIdx.x < 2 * SCAN_BLOCKS + MMW_BLOCKS) {
        mm_tile16(W01, W2, Wc, (blockIdx.x - 2 * SCAN_BLOCKS) * 16, t);
    } else if (blockIdx.x == 2 * SCAN_BLOCKS + MMW_BLOCKS) {
        vecmat128(bv01, W2, bc1, t);
    } else {
        vecmat128(b1, W2, bc2, t);
    }
}

// ---------------------------------------------------------------------------
// K3: hetero {block scan of cnt_in | dinv_io = dinv_out*dinv_in}
// ---------------------------------------------------------------------------

__global__ __launch_bounds__(256) void scan_dio_kernel(
        const int* __restrict__ cnt_in, int* __restrict__ row_off,
        int* __restrict__ blocksums,
        const float* __restrict__ dinv_out, const float* __restrict__ dinv_in,
        float* __restrict__ dinv_io) {
    int t = threadIdx.x;
    if (blockIdx.x < SCAN_BLOCKS) {
        __shared__ int s[256];
        int i = blockIdx.x * 256 + t;
        int v = (i < N_NODES) ? cnt_in[i] : 0;
        s[t] = v;
        __syncthreads();
        for (int offs = 1; offs < 256; offs <<= 1) {
            int add = (t >= offs) ? s[t - offs] : 0;
            __syncthreads();
            s[t] += add;
            __syncthreads();
        }
        if (i < N_NODES) row_off[i + 1] = s[t];
        if (t == 255) blocksums[blockIdx.x] = s[255];
    } else {
        int n = (blockIdx.x - SCAN_BLOCKS) * 256 + t;
        if (n < N_NODES) dinv_io[n] = dinv_out[n] * dinv_in[n];
    }
}

__global__ void scan_top_kernel(const int* __restrict__ blocksums, int* __restrict__ blockoffs,
                                int nblocks) {
    __shared__ int s[256];
    int t = threadIdx.x;
    int v = (t < nblocks) ? blocksums[t] : 0;
    s[t] = v;
    __syncthreads();
    for (int offs = 1; offs < 256; offs <<= 1) {
        int add = (t >= offs) ? s[t - offs] : 0;
        __syncthreads();
        s[t] += add;
        __syncthreads();
    }
    blockoffs[t] = s[t] - v;  // exclusive
}

__global__ void scan_add_kernel(int* __restrict__ outv, const int* __restrict__ blockoffs) {
    int i = blockIdx.x * 256 + threadIdx.x;
    if (i < N_NODES) outv[i + 1] += blockoffs[blockIdx.x];
    if (i == 0) outv[0] = 0;
}

// ---------------------------------------------------------------------------
// K6: hetero {fill CSR via LDS local positions (no global atomics) | prescale}
// ---------------------------------------------------------------------------

__global__ __launch_bounds__(256) void fill_prescale_kernel(
        const int* __restrict__ src, const int* __restrict__ dst,
        const int* __restrict__ row_off, const unsigned char* __restrict__ boff,
        int* __restrict__ csr_src,
        const float4* __restrict__ feat4, const float* __restrict__ dinv_out,
        float4* __restrict__ p04) {
    __shared__ unsigned int lcnt[HWORDS];
    int t = threadIdx.x;
    if (blockIdx.x < HB) {
        for (int i = t; i < HWORDS; i += 256) lcnt[i] = 0;
        __syncthreads();
        int b = blockIdx.x;
        int base = b * EPB;
        int end = base + EPB;
        const unsigned char* bo = boff + (size_t)b * N_NODES;
        for (int e = base + t; e < end; e += 256) {
            int d = dst[e];
            int sh = (d & 3) * 8;
            unsigned int old = atomicAdd(&lcnt[d >> 2], 1u << sh);
            int local = (int)((old >> sh) & 0xFFu);
            csr_src[row_off[d] + (int)bo[d] + local] = src[e];
        }
    } else {
        int i = (blockIdx.x - HB) * 256 + t;  // float4 index
        if (i < N_NODES * 32) {
            int n = i >> 5;
            float s = dinv_out[n];
            float4 v = feat4[i];
            float4 r;
            r.x = v.x * s; r.y = v.y * s; r.z = v.z * s; r.w = v.w * s;
            p04[i] = r;
        }
    }
}

// ---------------------------------------------------------------------------
// uvec body: o1[n] = s1[n]*sum g[s]; o2[n] = s2[n]*sum (optional)
// ---------------------------------------------------------------------------

__device__ __forceinline__ void uvec_body(int nb, int t,
        const int* __restrict__ csr_src, const int* __restrict__ row_off,
        const float* __restrict__ gvec, const float* __restrict__ s1,
        const float* __restrict__ s2, float* __restrict__ o1, float* __restrict__ o2) {
    int wave = t >> 6;
    int lane = t & 63;
    int n = nb * 4 + wave;
    if (n >= N_NODES) return;
    int start = row_off[n], end = row_off[n + 1];
    float a = 0.f;
    for (int j = start + lane; j < end; j += 64) a += gvec[csr_src[j]];
#pragma unroll
    for (int m = 32; m; m >>= 1) a += __shfl_xor(a, m, 64);
    if (lane == 0) {
        o1[n] = s1[n] * a;
        if (o2) o2[n] = s2[n] * a;
    }
}

// ---------------------------------------------------------------------------
// Row-major pull aggregation body (uniform-batch inner loop, R9-proven)
// ---------------------------------------------------------------------------

__device__ __forceinline__ void agg_row_body(const float4* __restrict__ h4,
                                             const int* __restrict__ csr_src,
                                             int start, int end, int lane, int hw, int l32,
                                             float4& accOut) {
    float4 a0 = make_float4(0.f, 0.f, 0.f, 0.f);
    float4 a1 = a0, a2 = a0, a3 = a0;
    for (int j0 = start; j0 < end; j0 += 64) {
        int jj = j0 + lane;
        int sv = (jj < end) ? csr_src[jj] : 0;
        int nj = min(64, end - j0);
        int i = 0;
        for (; i + 8 <= nj; i += 8) {
            int s0 = __shfl(sv, i + hw, 64);
            int s1 = __shfl(sv, i + 2 + hw, 64);
            int s2 = __shfl(sv, i + 4 + hw, 64);
            int s3 = __shfl(sv, i + 6 + hw, 64);
            float4 h0 = h4[(size_t)s0 * 32 + l32];
            float4 h1 = h4[(size_t)s1 * 32 + l32];
            float4 h2 = h4[(size_t)s2 * 32 + l32];
            float4 h3 = h4[(size_t)s3 * 32 + l32];
            a0.x += h0.x; a0.y += h0.y; a0.z += h0.z; a0.w += h0.w;
            a1.x += h1.x; a1.y += h1.y; a1.z += h1.z; a1.w += h1.w;
            a2.x += h2.x; a2.y += h2.y; a2.z += h2.z; a2.w += h2.w;
            a3.x += h3.x; a3.y += h3.y; a3.z += h3.z; a3.w += h3.w;
        }
        for (; i < nj; i += 2) {
            int idx = i + hw;
            int s = __shfl(sv, idx, 64);
            if (idx < nj) {
                float4 h0 = h4[(size_t)s * 32 + l32];
                a0.x += h0.x; a0.y += h0.y; a0.z += h0.z; a0.w += h0.w;
            }
        }
    }
    accOut.x = (a0.x + a1.x) + (a2.x + a3.x);
    accOut.y = (a0.y + a1.y) + (a2.y + a3.y);
    accOut.z = (a0.z + a1.z) + (a2.z + a3.z);
    accOut.w = (a0.w + a1.w) + (a2.w + a3.w);
}

// ---------------------------------------------------------------------------
// K7: parity-interleaved {agg1: p1 = Dio A p0 | uvec1: u1,u1s} + flag role
// ---------------------------------------------------------------------------

__global__ __launch_bounds__(256) void agg1_uvec1_flag_kernel(
        const float* __restrict__ p0, const int* __restrict__ csr_src,
        const int* __restrict__ row_off, const float* __restrict__ dinv_io,
        float* __restrict__ p1,
        const float* __restrict__ dinv_out, const float* __restrict__ dinv_in,
        float* __restrict__ u1, float* __restrict__ u1s,
        const int* __restrict__ labels, int* __restrict__ flag) {
    int t = threadIdx.x;
    if (blockIdx.x < 2 * UVEC_BLOCKS) {
        int grp = blockIdx.x >> 1;
        if (blockIdx.x & 1) {
            uvec_body(grp, t, csr_src, row_off, dinv_out, dinv_in, dinv_io, u1, u1s);
        } else {
            int wave = t >> 6;
            int lane = t & 63;
            int hw = lane >> 5, l32 = lane & 31;
            int n = grp * 4 + wave;
            if (n >= N_NODES) return;
            float4 acc;
            agg_row_body((const float4*)p0, csr_src, row_off[n], row_off[n + 1], lane, hw, l32,
                         acc);
            acc.x += __shfl_xor(acc.x, 32, 64);
            acc.y += __shfl_xor(acc.y, 32, 64);
            acc.z += __shfl_xor(acc.z, 32, 64);
            acc.w += __shfl_xor(acc.w, 32, 64);
            if (hw == 0) {
                float wi = dinv_io[n];
                float4 r;
                r.x = acc.x * wi; r.y = acc.y * wi; r.z = acc.z * wi; r.w = acc.w * wi;
                ((float4*)p1)[(size_t)n * 32 + l32] = r;
            }
        }
    } else {
        int i = (blockIdx.x - 2 * UVEC_BLOCKS) * 256 + t;
        if (i < N_LABELS) {
            int n = labels[i];
            int a = row_off[n], bnd = row_off[n + 1];
            for (int j = a; j < bnd; ++j) flag[csr_src[j]] = 1;
        }
    }
}

// ---------------------------------------------------------------------------
// K8: parity-interleaved {agg2: p2 = Dio A p1 on flagged rows | uvec2: u2}
// ---------------------------------------------------------------------------

__global__ __launch_bounds__(256) void agg2_uvec2_kernel(
        const float* __restrict__ p1, const int* __restrict__ csr_src,
        const int* __restrict__ row_off, const float* __restrict__ dinv_io,
        const int* __restrict__ flag, float* __restrict__ p2,
        const float* __restrict__ u1s, const float* __restrict__ dinv_in,
        float* __restrict__ u2) {
    int t = threadIdx.x;
    int grp = blockIdx.x >> 1;
    if (blockIdx.x & 1) {
        uvec_body(grp, t, csr_src, row_off, u1s, dinv_in, nullptr, u2, nullptr);
    } else {
        int wave = t >> 6;
        int lane = t & 63;
        int hw = lane >> 5, l32 = lane & 31;
        int n = grp * 4 + wave;
        if (n >= N_NODES) return;
        if (!flag[n]) return;
        float4 acc;
        agg_row_body((const float4*)p1, csr_src, row_off[n], row_off[n + 1], lane, hw, l32, acc);
        acc.x += __shfl_xor(acc.x, 32, 64);
        acc.y += __shfl_xor(acc.y, 32, 64);
        acc.z += __shfl_xor(acc.z, 32, 64);
        acc.w += __shfl_xor(acc.w, 32, 64);
        if (hw == 0) {
            float wi = dinv_io[n];
            float4 r;
            r.x = acc.x * wi; r.y = acc.y * wi; r.z = acc.z * wi; r.w = acc.w * wi;
            ((float4*)p2)[(size_t)n * 32 + l32] = r;
        }
    }
}

// ---------------------------------------------------------------------------
// K9: fused {label-row aggregation -> LDS | 16-row matmul vs Wc + rank-1 biases}
// ---------------------------------------------------------------------------

__global__ __launch_bounds__(256) void agg_label_matmul_kernel(
        const float* __restrict__ p2, const int* __restrict__ csr_src,
        const int* __restrict__ row_off, const float* __restrict__ dinv_in,
        const int* __restrict__ labels,
        const float* __restrict__ Wc, const float* __restrict__ bc1,
        const float* __restrict__ bc2, const float* __restrict__ b2,
        const float* __restrict__ u1, const float* __restrict__ u2,
        float* __restrict__ outbuf) {
    __shared__ float tl[16][D];
    int t = threadIdx.x;
    int wave = t >> 6, lane = t & 63;
    int hw = lane >> 5, l32 = lane & 31;
    int rbase = blockIdx.x * 16;
#pragma unroll
    for (int rr = 0; rr < 4; ++rr) {
        int row = rbase + wave * 4 + rr;
        int n = labels[row];
        float4 acc;
        agg_row_body((const float4*)p2, csr_src, row_off[n], row_off[n + 1], lane, hw, l32, acc);
        acc.x += __shfl_xor(acc.x, 32, 64);
        acc.y += __shfl_xor(acc.y, 32, 64);
        acc.z += __shfl_xor(acc.z, 32, 64);
        acc.w += __shfl_xor(acc.w, 32, 64);
        if (hw == 0) {
            float wi = dinv_in[n];
            float4 r;
            r.x = acc.x * wi; r.y = acc.y * wi; r.z = acc.z * wi; r.w = acc.w * wi;
            ((float4*)&tl[wave * 4 + rr][0])[l32] = r;
        }
    }
    __syncthreads();

    int tx = t & 15, ty = t >> 4;
    int r = rbase + ty;
    int lab = labels[r];
    float s2 = u2[lab], s1 = u1[lab];
    float4 c10 = ((const float4*)bc1)[tx * 2];
    float4 c11 = ((const float4*)bc1)[tx * 2 + 1];
    float4 c20 = ((const float4*)bc2)[tx * 2];
    float4 c21 = ((const float4*)bc2)[tx * 2 + 1];
    float4 bz0 = ((const float4*)b2)[tx * 2];
    float4 bz1 = ((const float4*)b2)[tx * 2 + 1];

    float acc[8];
    acc[0] = fmaf(s2, c10.x, fmaf(s1, c20.x, bz0.x));
    acc[1] = fmaf(s2, c10.y, fmaf(s1, c20.y, bz0.y));
    acc[2] = fmaf(s2, c10.z, fmaf(s1, c20.z, bz0.z));
    acc[3] = fmaf(s2, c10.w, fmaf(s1, c20.w, bz0.w));
    acc[4] = fmaf(s2, c11.x, fmaf(s1, c21.x, bz1.x));
    acc[5] = fmaf(s2, c11.y, fmaf(s1, c21.y, bz1.y));
    acc[6] = fmaf(s2, c11.z, fmaf(s1, c21.z, bz1.z));
    acc[7] = fmaf(s2, c11.w, fmaf(s1, c21.w, bz1.w));

    const float4* W4 = (const float4*)Wc;
#pragma unroll 4
    for (int kb = 0; kb < 32; ++kb) {
        float4 a = ((const float4*)&tl[ty][0])[kb];
        int k4 = kb * 4;
        MM16_STEP(0, x)
        MM16_STEP(1, y)
        MM16_STEP(2, z)
        MM16_STEP(3, w)
    }

    float4 o0, o1;
    o0.x = acc[0]; o0.y = acc[1]; o0.z = acc[2]; o0.w = acc[3];
    o1.x = acc[4]; o1.y = acc[5]; o1.z = acc[6]; o1.w = acc[7];
    float4* op = (float4*)&outbuf[(size_t)r * D + tx * 8];
    op[0] = o0;
    op[1] = o1;
}

// ---------------------------------------------------------------------------

extern "C" void kernel_launch(void* const* d_in, const int* in_sizes, int n_in,
                              void* d_out, int out_size, void* d_ws, size_t ws_size,
                              hipStream_t stream) {
    const int* labels = (const int*)d_in[0];
    const int* src    = (const int*)d_in[1];
    const int* dst    = (const int*)d_in[2];
    const float* feat = (const float*)d_in[3];
    const float* W0   = (const float*)d_in[4];
    const float* b0   = (const float*)d_in[5];
    const float* W1   = (const float*)d_in[6];
    const float* b1   = (const float*)d_in[7];
    const float* W2   = (const float*)d_in[8];
    const float* b2   = (const float*)d_in[9];
    float* out = (float*)d_out;

    char* ws = (char*)d_ws;
    size_t off = 0;
    auto alloc = [&](size_t bytes) -> void* {
        void* p = ws + off;
        off = (off + bytes + 255) & ~(size_t)255;
        return p;
    };
    int* row_off    = (int*)alloc((N_NODES + 1) * 4);
    int* blocksums  = (int*)alloc(256 * 4);
    int* blockoffs  = (int*)alloc(256 * 4);
    int* csr_src    = (int*)alloc((size_t)N_EDGES * 4);
    int* cnt_in     = (int*)alloc(N_NODES * 4);
    int* flag       = (int*)alloc(N_NODES * 4);
    float* dinv_out = (float*)alloc(N_NODES * 4);
    float* dinv_in  = (float*)alloc(N_NODES * 4);
    float* dinv_io  = (float*)alloc(N_NODES * 4);
    float* u1       = (float*)alloc(N_NODES * 4);
    float* u1s      = (float*)alloc(N_NODES * 4);
    float* u2       = (float*)alloc(N_NODES * 4);
    float* W01      = (float*)alloc((size_t)D * D * 4);
    float* Wc       = (float*)alloc((size_t)D * D * 4);
    float* bv01     = (float*)alloc(D * 4);
    float* bc1      = (float*)alloc(D * 4);
    float* bc2      = (float*)alloc(D * 4);
    unsigned char* boff = (unsigned char*)alloc((size_t)HB * N_NODES);  // 12.8 MB
    float* BUF1 = (float*)alloc((size_t)N_NODES * D * 4);  // p0 | p2
    float* BUF2 = (float*)alloc((size_t)N_NODES * D * 4);  // Hsrc+Hdst | p1

    // aliases (stream-ordered lifetimes):
    unsigned int* Hsrc = (unsigned int*)BUF2;                       // dead after K2
    unsigned int* Hdst = (unsigned int*)BUF2 + (size_t)HB * HWORDS; // dead after K2
    float* p0 = BUF1;   // written K6, read K7
    float* p1 = BUF2;   // written K7, read K8
    float* p2 = BUF1;   // p0 dead after K7

    hipMemsetAsync(flag, 0, N_NODES * 4, stream);

    // K1: src hist + dst hist + W01 + bv01 (zero global atomics)
    hist2_w_kernel<<<2 * HB + MMW_BLOCKS + 1, 256, 0, stream>>>(
        src, dst, Hsrc, Hdst, W0, W1, b0, W01, bv01);
    // K2: merges + Wc + bc1 + bc2
    merge_w_kernel<<<2 * SCAN_BLOCKS + MMW_BLOCKS + 2, 256, 0, stream>>>(
        Hsrc, Hdst, dinv_out, dinv_in, cnt_in, boff, W01, W2, bv01, b1, Wc, bc1, bc2);
    // K3: scan(cnt_in) + dinv_io
    scan_dio_kernel<<<2 * SCAN_BLOCKS, 256, 0, stream>>>(
        cnt_in, row_off, blocksums, dinv_out, dinv_in, dinv_io);
    // K4-5: finish row_off scan
    scan_top_kernel<<<1, 256, 0, stream>>>(blocksums, blockoffs, SCAN_BLOCKS);
    scan_add_kernel<<<SCAN_BLOCKS, 256, 0, stream>>>(row_off, blockoffs);
    // K6: fill (LDS local positions) + prescale
    fill_prescale_kernel<<<HB + PRESCALE_BLOCKS, 256, 0, stream>>>(
        src, dst, row_off, boff, csr_src, (const float4*)feat, dinv_out, (float4*)p0);
    // K7: agg1 ∥ uvec1 (parity-interleaved) + flag
    agg1_uvec1_flag_kernel<<<2 * UVEC_BLOCKS + FLAG_BLOCKS, 256, 0, stream>>>(
        p0, csr_src, row_off, dinv_io, p1, dinv_out, dinv_in, u1, u1s, labels, flag);
    // K8: agg2 (flag-guarded) ∥ uvec2 (parity-interleaved)
    agg2_uvec2_kernel<<<2 * UVEC_BLOCKS, 256, 0, stream>>>(
        p1, csr_src, row_off, dinv_io, flag, p2, u1s, dinv_in, u2);
    // K9: fused label agg + final matmul
    agg_label_matmul_kernel<<<N_LABELS / 16, 256, 0, stream>>>(
        p2, csr_src, row_off, dinv_in, labels, Wc, bc1, bc2, b2, u1, u2, out);
}

// Round 13
// 202.198 us; speedup vs baseline: 1.1764x; 1.1764x over previous
//
#include <hip/hip_runtime.h>

#define N_NODES 50000
#define N_EDGES 800000
#define D 128
#define N_LABELS 4096
#define HB 256           // histogram blocks (3125 edges each, exact)
#define HWORDS 12500     // 50000/4 packed u8 counters per block (50 KB LDS)
#define EPB (N_EDGES / HB)     // 3125 edges per hist/fill block
#define PRESCALE_BLOCKS 6250   // N_NODES*32 float4 / 256
#define AGG_BLOCKS 12500       // 4 nodes per block
#define FLAG_BLOCKS 16         // 4096 labels / 256
#define SCAN_BLOCKS 196
#define MMW_BLOCKS 8           // 128x128 matmul, 16 rows/block

// ---------------------------------------------------------------------------
// small dense helpers (fp32, no LDS, W L1/L2-resident)
// ---------------------------------------------------------------------------

#define MM16_STEP(kk, comp)                                           \
    {                                                                 \
        float4 w0 = W4[(size_t)(k4 + kk) * 32 + tx * 2];              \
        float4 w1 = W4[(size_t)(k4 + kk) * 32 + tx * 2 + 1];          \
        acc[0] = fmaf(a.comp, w0.x, acc[0]);                          \
        acc[1] = fmaf(a.comp, w0.y, acc[1]);                          \
        acc[2] = fmaf(a.comp, w0.z, acc[2]);                          \
        acc[3] = fmaf(a.comp, w0.w, acc[3]);                          \
        acc[4] = fmaf(a.comp, w1.x, acc[4]);                          \
        acc[5] = fmaf(a.comp, w1.y, acc[5]);                          \
        acc[6] = fmaf(a.comp, w1.z, acc[6]);                          \
        acc[7] = fmaf(a.comp, w1.w, acc[7]);                          \
    }

__device__ __forceinline__ void mm_tile16(const float* __restrict__ A,
                                          const float* __restrict__ W,
                                          float* __restrict__ C, int r0, int t) {
    int tx = t & 15, ty = t >> 4;
    int r = r0 + ty;
    const float4* A4 = (const float4*)A;
    const float4* W4 = (const float4*)W;
    float acc[8] = {0.f, 0.f, 0.f, 0.f, 0.f, 0.f, 0.f, 0.f};
#pragma unroll 4
    for (int kb = 0; kb < 32; ++kb) {
        float4 a = A4[(size_t)r * 32 + kb];
        int k4 = kb * 4;
        MM16_STEP(0, x)
        MM16_STEP(1, y)
        MM16_STEP(2, z)
        MM16_STEP(3, w)
    }
    float4* cp = (float4*)&C[(size_t)r * D + tx * 8];
    float4 o0, o1;
    o0.x = acc[0]; o0.y = acc[1]; o0.z = acc[2]; o0.w = acc[3];
    o1.x = acc[4]; o1.y = acc[5]; o1.z = acc[6]; o1.w = acc[7];
    cp[0] = o0;
    cp[1] = o1;
}

__device__ __forceinline__ void vecmat128(const float* __restrict__ v,
                                          const float* __restrict__ W,
                                          float* __restrict__ outp, int t) {
    if (t < D) {
        float acc = 0.f;
#pragma unroll 8
        for (int k = 0; k < D; ++k) acc = fmaf(v[k], W[(size_t)k * D + t], acc);
        outp[t] = acc;
    }
}

// ---------------------------------------------------------------------------
// K1: hetero {src LDS histogram | dst LDS histogram | W01 = W0@W1 | bv01 = b0@W1}
// no global atomics anywhere
// ---------------------------------------------------------------------------

__global__ __launch_bounds__(256) void hist2_w_kernel(
        const int* __restrict__ src, const int* __restrict__ dst,
        unsigned int* __restrict__ Hsrc, unsigned int* __restrict__ Hdst,
        const float* __restrict__ W0, const float* __restrict__ W1,
        const float* __restrict__ b0, float* __restrict__ W01,
        float* __restrict__ bv01) {
    __shared__ unsigned int hist[HWORDS];
    int t = threadIdx.x;
    if (blockIdx.x < 2 * HB) {
        int isDst = (blockIdx.x >= HB);
        int hb = isDst ? (blockIdx.x - HB) : blockIdx.x;
        const int* keys = isDst ? dst : src;
        unsigned int* Hout = isDst ? Hdst : Hsrc;
        for (int i = t; i < HWORDS; i += 256) hist[i] = 0;
        __syncthreads();
        int base = hb * EPB;
        int end = base + EPB;
        for (int e = base + t; e < end; e += 256) {
            int n = keys[e];
            atomicAdd(&hist[n >> 2], 1u << ((n & 3) * 8));
        }
        __syncthreads();
        unsigned int* outp = Hout + (size_t)hb * HWORDS;
        for (int i = t; i < HWORDS; i += 256) outp[i] = hist[i];
    } else if (blockIdx.x < 2 * HB + MMW_BLOCKS) {
        mm_tile16(W0, W1, W01, (blockIdx.x - 2 * HB) * 16, t);
    } else {
        vecmat128(b0, W1, bv01, t);
    }
}

// ---------------------------------------------------------------------------
// K2: hetero {src merge -> dinv_out | dst merge -> boff,cnt_in,dinv_in |
//             Wc = W01@W2 | bc1 = bv01@W2 | bc2 = b1@W2}
// ---------------------------------------------------------------------------

__global__ __launch_bounds__(256) void merge_w_kernel(
        const unsigned int* __restrict__ Hsrc, const unsigned int* __restrict__ Hdst,
        float* __restrict__ dinv_out, float* __restrict__ dinv_in,
        int* __restrict__ cnt_in, unsigned char* __restrict__ boff,
        const float* __restrict__ W01, const float* __restrict__ W2,
        const float* __restrict__ bv01, const float* __restrict__ b1,
        float* __restrict__ Wc, float* __restrict__ bc1, float* __restrict__ bc2) {
    int t = threadIdx.x;
    if (blockIdx.x < SCAN_BLOCKS) {
        int n = blockIdx.x * 256 + t;
        if (n >= N_NODES) return;
        int w = n >> 2, sh = (n & 3) * 8;
        unsigned int s = 0;
#pragma unroll 8
        for (int b = 0; b < HB; ++b) s += (Hsrc[(size_t)b * HWORDS + w] >> sh) & 0xFFu;
        dinv_out[n] = (s > 0) ? 1.0f / sqrtf((float)s) : 0.0f;
    } else if (blockIdx.x < 2 * SCAN_BLOCKS) {
        int n = (blockIdx.x - SCAN_BLOCKS) * 256 + t;
        if (n >= N_NODES) return;
        int w = n >> 2, sh = (n & 3) * 8;
        unsigned int run = 0;
        for (int b = 0; b < HB; ++b) {
            boff[(size_t)b * N_NODES + n] = (unsigned char)run;
            run += (Hdst[(size_t)b * HWORDS + w] >> sh) & 0xFFu;
        }
        cnt_in[n] = (int)run;
        dinv_in[n] = (run > 0) ? 1.0f / sqrtf((float)run) : 0.0f;
    } else if (blockIdx.x < 2 * SCAN_BLOCKS + MMW_BLOCKS) {
        mm_tile16(W01, W2, Wc, (blockIdx.x - 2 * SCAN_BLOCKS) * 16, t);
    } else if (blockIdx.x == 2 * SCAN_BLOCKS + MMW_BLOCKS) {
        vecmat128(bv01, W2, bc1, t);
    } else {
        vecmat128(b1, W2, bc2, t);
    }
}

// ---------------------------------------------------------------------------
// K3: hetero {block scan of cnt_in | dinv_io = dinv_out*dinv_in}
// ---------------------------------------------------------------------------

__global__ __launch_bounds__(256) void scan_dio_kernel(
        const int* __restrict__ cnt_in, int* __restrict__ row_off,
        int* __restrict__ blocksums,
        const float* __restrict__ dinv_out, const float* __restrict__ dinv_in,
        float* __restrict__ dinv_io) {
    int t = threadIdx.x;
    if (blockIdx.x < SCAN_BLOCKS) {
        __shared__ int s[256];
        int i = blockIdx.x * 256 + t;
        int v = (i < N_NODES) ? cnt_in[i] : 0;
        s[t] = v;
        __syncthreads();
        for (int offs = 1; offs < 256; offs <<= 1) {
            int add = (t >= offs) ? s[t - offs] : 0;
            __syncthreads();
            s[t] += add;
            __syncthreads();
        }
        if (i < N_NODES) row_off[i + 1] = s[t];
        if (t == 255) blocksums[blockIdx.x] = s[255];
    } else {
        int n = (blockIdx.x - SCAN_BLOCKS) * 256 + t;
        if (n < N_NODES) dinv_io[n] = dinv_out[n] * dinv_in[n];
    }
}

__global__ void scan_top_kernel(const int* __restrict__ blocksums, int* __restrict__ blockoffs,
                                int nblocks) {
    __shared__ int s[256];
    int t = threadIdx.x;
    int v = (t < nblocks) ? blocksums[t] : 0;
    s[t] = v;
    __syncthreads();
    for (int offs = 1; offs < 256; offs <<= 1) {
        int add = (t >= offs) ? s[t - offs] : 0;
        __syncthreads();
        s[t] += add;
        __syncthreads();
    }
    blockoffs[t] = s[t] - v;  // exclusive
}

__global__ void scan_add_kernel(int* __restrict__ outv, const int* __restrict__ blockoffs) {
    int i = blockIdx.x * 256 + threadIdx.x;
    if (i < N_NODES) outv[i + 1] += blockoffs[blockIdx.x];
    if (i == 0) outv[0] = 0;
}

// ---------------------------------------------------------------------------
// K6: hetero {fill CSR via LDS local positions (no global atomics) | prescale}
// ---------------------------------------------------------------------------

__global__ __launch_bounds__(256) void fill_prescale_kernel(
        const int* __restrict__ src, const int* __restrict__ dst,
        const int* __restrict__ row_off, const unsigned char* __restrict__ boff,
        int* __restrict__ csr_src,
        const float4* __restrict__ feat4, const float* __restrict__ dinv_out,
        float4* __restrict__ p04) {
    __shared__ unsigned int lcnt[HWORDS];
    int t = threadIdx.x;
    if (blockIdx.x < HB) {
        for (int i = t; i < HWORDS; i += 256) lcnt[i] = 0;
        __syncthreads();
        int b = blockIdx.x;
        int base = b * EPB;
        int end = base + EPB;
        const unsigned char* bo = boff + (size_t)b * N_NODES;
        for (int e = base + t; e < end; e += 256) {
            int d = dst[e];
            int sh = (d & 3) * 8;
            unsigned int old = atomicAdd(&lcnt[d >> 2], 1u << sh);
            int local = (int)((old >> sh) & 0xFFu);
            csr_src[row_off[d] + (int)bo[d] + local] = src[e];
        }
    } else {
        int i = (blockIdx.x - HB) * 256 + t;  // float4 index
        if (i < N_NODES * 32) {
            int n = i >> 5;
            float s = dinv_out[n];
            float4 v = feat4[i];
            float4 r;
            r.x = v.x * s; r.y = v.y * s; r.z = v.z * s; r.w = v.w * s;
            p04[i] = r;
        }
    }
}

// ---------------------------------------------------------------------------
// Row-major pull aggregation body with optional fused scalar-table sums:
//   acc = sum h4[s]; ws1 = sum wtab1[s]; ws2 = sum wtab2[s]  (per half-wave
//   partials — caller reduces across half-waves via shfl_xor(·,32)).
// wtab* == nullptr compiles the scalar path out (identical to proven body).
// ---------------------------------------------------------------------------

__device__ __forceinline__ void agg_row_body(const float4* __restrict__ h4,
                                             const int* __restrict__ csr_src,
                                             const float* __restrict__ wtab1,
                                             const float* __restrict__ wtab2,
                                             int start, int end, int lane, int hw, int l32,
                                             float4& accOut, float& ws1, float& ws2) {
    float4 a0 = make_float4(0.f, 0.f, 0.f, 0.f);
    float4 a1 = a0, a2 = a0, a3 = a0;
    float w1a = 0.f, w2a = 0.f;
    for (int j0 = start; j0 < end; j0 += 64) {
        int jj = j0 + lane;
        int sv = (jj < end) ? csr_src[jj] : 0;
        int nj = min(64, end - j0);
        int i = 0;
        for (; i + 8 <= nj; i += 8) {
            int s0 = __shfl(sv, i + hw, 64);
            int s1 = __shfl(sv, i + 2 + hw, 64);
            int s2 = __shfl(sv, i + 4 + hw, 64);
            int s3 = __shfl(sv, i + 6 + hw, 64);
            float4 h0 = h4[(size_t)s0 * 32 + l32];
            float4 h1 = h4[(size_t)s1 * 32 + l32];
            float4 h2 = h4[(size_t)s2 * 32 + l32];
            float4 h3 = h4[(size_t)s3 * 32 + l32];
            if (wtab1) w1a += (wtab1[s0] + wtab1[s1]) + (wtab1[s2] + wtab1[s3]);
            if (wtab2) w2a += (wtab2[s0] + wtab2[s1]) + (wtab2[s2] + wtab2[s3]);
            a0.x += h0.x; a0.y += h0.y; a0.z += h0.z; a0.w += h0.w;
            a1.x += h1.x; a1.y += h1.y; a1.z += h1.z; a1.w += h1.w;
            a2.x += h2.x; a2.y += h2.y; a2.z += h2.z; a2.w += h2.w;
            a3.x += h3.x; a3.y += h3.y; a3.z += h3.z; a3.w += h3.w;
        }
        for (; i < nj; i += 2) {
            int idx = i + hw;
            int s = __shfl(sv, idx, 64);
            if (idx < nj) {
                float4 h0 = h4[(size_t)s * 32 + l32];
                if (wtab1) w1a += wtab1[s];
                if (wtab2) w2a += wtab2[s];
                a0.x += h0.x; a0.y += h0.y; a0.z += h0.z; a0.w += h0.w;
            }
        }
    }
    accOut.x = (a0.x + a1.x) + (a2.x + a3.x);
    accOut.y = (a0.y + a1.y) + (a2.y + a3.y);
    accOut.z = (a0.z + a1.z) + (a2.z + a3.z);
    accOut.w = (a0.w + a1.w) + (a2.w + a3.w);
    ws1 = w1a;
    ws2 = w2a;
}

// ---------------------------------------------------------------------------
// K7: sequential roles {agg1: p1 = Dio A p0 | flag label-edge sources}
// ---------------------------------------------------------------------------

__global__ __launch_bounds__(256) void agg1_flag_kernel(
        const float* __restrict__ p0, const int* __restrict__ csr_src,
        const int* __restrict__ row_off, const float* __restrict__ dinv_io,
        float* __restrict__ p1,
        const int* __restrict__ labels, int* __restrict__ flag) {
    int t = threadIdx.x;
    if (blockIdx.x < AGG_BLOCKS) {
        int wave = t >> 6;
        int lane = t & 63;
        int hw = lane >> 5, l32 = lane & 31;
        int n = blockIdx.x * 4 + wave;
        if (n >= N_NODES) return;
        float4 acc;
        float d1, d2;
        agg_row_body((const float4*)p0, csr_src, nullptr, nullptr,
                     row_off[n], row_off[n + 1], lane, hw, l32, acc, d1, d2);
        acc.x += __shfl_xor(acc.x, 32, 64);
        acc.y += __shfl_xor(acc.y, 32, 64);
        acc.z += __shfl_xor(acc.z, 32, 64);
        acc.w += __shfl_xor(acc.w, 32, 64);
        if (hw == 0) {
            float wi = dinv_io[n];
            float4 r;
            r.x = acc.x * wi; r.y = acc.y * wi; r.z = acc.z * wi; r.w = acc.w * wi;
            ((float4*)p1)[(size_t)n * 32 + l32] = r;
        }
    } else {
        int i = (blockIdx.x - AGG_BLOCKS) * 256 + t;
        if (i < N_LABELS) {
            int n = labels[i];
            int a = row_off[n], bnd = row_off[n + 1];
            for (int j = a; j < bnd; ++j) flag[csr_src[j]] = 1;
        }
    }
}

// ---------------------------------------------------------------------------
// K8: agg2 on flagged rows with fused u1s: p2 = Dio A p1 ; u1s = Dio * sum dinv_out[s]
// ---------------------------------------------------------------------------

__global__ __launch_bounds__(256) void agg2_kernel(
        const float* __restrict__ p1, const int* __restrict__ csr_src,
        const int* __restrict__ row_off, const float* __restrict__ dinv_io,
        const int* __restrict__ flag, float* __restrict__ p2,
        const float* __restrict__ dinv_out, float* __restrict__ u1s) {
    int t = threadIdx.x;
    int wave = t >> 6;
    int lane = t & 63;
    int hw = lane >> 5, l32 = lane & 31;
    int n = blockIdx.x * 4 + wave;
    if (n >= N_NODES) return;
    if (!flag[n]) return;
    float4 acc;
    float ws1, d2;
    agg_row_body((const float4*)p1, csr_src, dinv_out, nullptr,
                 row_off[n], row_off[n + 1], lane, hw, l32, acc, ws1, d2);
    acc.x += __shfl_xor(acc.x, 32, 64);
    acc.y += __shfl_xor(acc.y, 32, 64);
    acc.z += __shfl_xor(acc.z, 32, 64);
    acc.w += __shfl_xor(acc.w, 32, 64);
    ws1 += __shfl_xor(ws1, 32, 64);
    float wi = dinv_io[n];
    if (lane == 0) u1s[n] = wi * ws1;
    if (hw == 0) {
        float4 r;
        r.x = acc.x * wi; r.y = acc.y * wi; r.z = acc.z * wi; r.w = acc.w * wi;
        ((float4*)p2)[(size_t)n * 32 + l32] = r;
    }
}

// ---------------------------------------------------------------------------
// K9: fused {label agg (+ scalar sums for u1,u2) -> LDS | 16-row matmul vs Wc}
//   t_r  = dinv_in[n] * (A p2)[n]
//   u1_r = dinv_in[n] * sum dinv_out[s] ; u2_r = dinv_in[n] * sum u1s[s]
//   out[r] = t_r @ Wc + u2_r*bc1 + u1_r*bc2 + b2
// ---------------------------------------------------------------------------

__global__ __launch_bounds__(256) void agg_label_matmul_kernel(
        const float* __restrict__ p2, const int* __restrict__ csr_src,
        const int* __restrict__ row_off, const float* __restrict__ dinv_in,
        const int* __restrict__ labels,
        const float* __restrict__ dinv_out, const float* __restrict__ u1s,
        const float* __restrict__ Wc, const float* __restrict__ bc1,
        const float* __restrict__ bc2, const float* __restrict__ b2,
        float* __restrict__ outbuf) {
    __shared__ float tl[16][D];
    __shared__ float sb[16][2];
    int t = threadIdx.x;
    int wave = t >> 6, lane = t & 63;
    int hw = lane >> 5, l32 = lane & 31;
    int rbase = blockIdx.x * 16;
#pragma unroll
    for (int rr = 0; rr < 4; ++rr) {
        int row = rbase + wave * 4 + rr;
        int n = labels[row];
        float4 acc;
        float ws1, ws2;
        agg_row_body((const float4*)p2, csr_src, dinv_out, u1s,
                     row_off[n], row_off[n + 1], lane, hw, l32, acc, ws1, ws2);
        acc.x += __shfl_xor(acc.x, 32, 64);
        acc.y += __shfl_xor(acc.y, 32, 64);
        acc.z += __shfl_xor(acc.z, 32, 64);
        acc.w += __shfl_xor(acc.w, 32, 64);
        ws1 += __shfl_xor(ws1, 32, 64);
        ws2 += __shfl_xor(ws2, 32, 64);
        float wi = dinv_in[n];
        if (lane == 0) {
            sb[wave * 4 + rr][0] = wi * ws1;  // u1 at this label row
            sb[wave * 4 + rr][1] = wi * ws2;  // u2 at this label row
        }
        if (hw == 0) {
            float4 r;
            r.x = acc.x * wi; r.y = acc.y * wi; r.z = acc.z * wi; r.w = acc.w * wi;
            ((float4*)&tl[wave * 4 + rr][0])[l32] = r;
        }
    }
    __syncthreads();

    int tx = t & 15, ty = t >> 4;
    int r = rbase + ty;
    float s1 = sb[ty][0], s2 = sb[ty][1];
    float4 c10 = ((const float4*)bc1)[tx * 2];
    float4 c11 = ((const float4*)bc1)[tx * 2 + 1];
    float4 c20 = ((const float4*)bc2)[tx * 2];
    float4 c21 = ((const float4*)bc2)[tx * 2 + 1];
    float4 bz0 = ((const float4*)b2)[tx * 2];
    float4 bz1 = ((const float4*)b2)[tx * 2 + 1];

    float acc[8];
    acc[0] = fmaf(s2, c10.x, fmaf(s1, c20.x, bz0.x));
    acc[1] = fmaf(s2, c10.y, fmaf(s1, c20.y, bz0.y));
    acc[2] = fmaf(s2, c10.z, fmaf(s1, c20.z, bz0.z));
    acc[3] = fmaf(s2, c10.w, fmaf(s1, c20.w, bz0.w));
    acc[4] = fmaf(s2, c11.x, fmaf(s1, c21.x, bz1.x));
    acc[5] = fmaf(s2, c11.y, fmaf(s1, c21.y, bz1.y));
    acc[6] = fmaf(s2, c11.z, fmaf(s1, c21.z, bz1.z));
    acc[7] = fmaf(s2, c11.w, fmaf(s1, c21.w, bz1.w));

    const float4* W4 = (const float4*)Wc;
#pragma unroll 4
    for (int kb = 0; kb < 32; ++kb) {
        float4 a = ((const float4*)&tl[ty][0])[kb];
        int k4 = kb * 4;
        MM16_STEP(0, x)
        MM16_STEP(1, y)
        MM16_STEP(2, z)
        MM16_STEP(3, w)
    }

    float4 o0, o1;
    o0.x = acc[0]; o0.y = acc[1]; o0.z = acc[2]; o0.w = acc[3];
    o1.x = acc[4]; o1.y = acc[5]; o1.z = acc[6]; o1.w = acc[7];
    float4* op = (float4*)&outbuf[(size_t)r * D + tx * 8];
    op[0] = o0;
    op[1] = o1;
}

// ---------------------------------------------------------------------------

extern "C" void kernel_launch(void* const* d_in, const int* in_sizes, int n_in,
                              void* d_out, int out_size, void* d_ws, size_t ws_size,
                              hipStream_t stream) {
    const int* labels = (const int*)d_in[0];
    const int* src    = (const int*)d_in[1];
    const int* dst    = (const int*)d_in[2];
    const float* feat = (const float*)d_in[3];
    const float* W0   = (const float*)d_in[4];
    const float* b0   = (const float*)d_in[5];
    const float* W1   = (const float*)d_in[6];
    const float* b1   = (const float*)d_in[7];
    const float* W2   = (const float*)d_in[8];
    const float* b2   = (const float*)d_in[9];
    float* out = (float*)d_out;

    char* ws = (char*)d_ws;
    size_t off = 0;
    auto alloc = [&](size_t bytes) -> void* {
        void* p = ws + off;
        off = (off + bytes + 255) & ~(size_t)255;
        return p;
    };
    int* row_off    = (int*)alloc((N_NODES + 1) * 4);
    int* blocksums  = (int*)alloc(256 * 4);
    int* blockoffs  = (int*)alloc(256 * 4);
    int* csr_src    = (int*)alloc((size_t)N_EDGES * 4);
    int* cnt_in     = (int*)alloc(N_NODES * 4);
    int* flag       = (int*)alloc(N_NODES * 4);
    float* dinv_out = (float*)alloc(N_NODES * 4);
    float* dinv_in  = (float*)alloc(N_NODES * 4);
    float* dinv_io  = (float*)alloc(N_NODES * 4);
    float* u1s      = (float*)alloc(N_NODES * 4);
    float* W01      = (float*)alloc((size_t)D * D * 4);
    float* Wc       = (float*)alloc((size_t)D * D * 4);
    float* bv01     = (float*)alloc(D * 4);
    float* bc1      = (float*)alloc(D * 4);
    float* bc2      = (float*)alloc(D * 4);
    unsigned char* boff = (unsigned char*)alloc((size_t)HB * N_NODES);  // 12.8 MB
    float* BUF1 = (float*)alloc((size_t)N_NODES * D * 4);  // p0 | p2
    float* BUF2 = (float*)alloc((size_t)N_NODES * D * 4);  // Hsrc+Hdst | p1

    // aliases (stream-ordered lifetimes):
    unsigned int* Hsrc = (unsigned int*)BUF2;                       // dead after K2
    unsigned int* Hdst = (unsigned int*)BUF2 + (size_t)HB * HWORDS; // dead after K2
    float* p0 = BUF1;   // written K6, read K7
    float* p1 = BUF2;   // written K7, read K8
    float* p2 = BUF1;   // p0 dead after K7

    hipMemsetAsync(flag, 0, N_NODES * 4, stream);

    // K1: src hist + dst hist + W01 + bv01 (zero global atomics)
    hist2_w_kernel<<<2 * HB + MMW_BLOCKS + 1, 256, 0, stream>>>(
        src, dst, Hsrc, Hdst, W0, W1, b0, W01, bv01);
    // K2: merges + Wc + bc1 + bc2
    merge_w_kernel<<<2 * SCAN_BLOCKS + MMW_BLOCKS + 2, 256, 0, stream>>>(
        Hsrc, Hdst, dinv_out, dinv_in, cnt_in, boff, W01, W2, bv01, b1, Wc, bc1, bc2);
    // K3: scan(cnt_in) + dinv_io
    scan_dio_kernel<<<2 * SCAN_BLOCKS, 256, 0, stream>>>(
        cnt_in, row_off, blocksums, dinv_out, dinv_in, dinv_io);
    // K4-5: finish row_off scan
    scan_top_kernel<<<1, 256, 0, stream>>>(blocksums, blockoffs, SCAN_BLOCKS);
    scan_add_kernel<<<SCAN_BLOCKS, 256, 0, stream>>>(row_off, blockoffs);
    // K6: fill (LDS local positions) + prescale
    fill_prescale_kernel<<<HB + PRESCALE_BLOCKS, 256, 0, stream>>>(
        src, dst, row_off, boff, csr_src, (const float4*)feat, dinv_out, (float4*)p0);
    // K7: agg1 + flag (sequential roles)
    agg1_flag_kernel<<<AGG_BLOCKS + FLAG_BLOCKS, 256, 0, stream>>>(
        p0, csr_src, row_off, dinv_io, p1, labels, flag);
    // K8: agg2 on flagged rows, fused u1s
    agg2_kernel<<<AGG_BLOCKS, 256, 0, stream>>>(
        p1, csr_src, row_off, dinv_io, flag, p2, dinv_out, u1s);
    // K9: fused label agg (+u1,u2 scalar sums) + final matmul
    agg_label_matmul_kernel<<<N_LABELS / 16, 256, 0, stream>>>(
        p2, csr_src, row_off, dinv_in, labels, dinv_out, u1s, Wc, bc1, bc2, b2, out);
}

// Round 14
// 154.864 us; speedup vs baseline: 1.5359x; 1.3056x over previous
//
#include <hip/hip_runtime.h>
#include <hip/hip_fp16.h>

#define N_NODES 50000
#define N_EDGES 800000
#define D 128
#define N_LABELS 4096
#define HB 256           // histogram blocks (3125 edges each, exact)
#define HWORDS 12500     // 50000/4 packed u8 counters per block (50 KB LDS)
#define EPB (N_EDGES / HB)     // 3125 edges per hist/fill block
#define PRESCALE_BLOCKS 3125   // N_NODES*16 half8-chunks / 256
#define AGG_BLOCKS 12500       // 4 nodes per block
#define FLAG_BLOCKS 16         // 4096 labels / 256
#define SCAN_BLOCKS 196
#define MMW_BLOCKS 8           // 128x128 matmul, 16 rows/block

// ---------------------------------------------------------------------------
// fp16 helpers: tables store 128 halves/row (256 B); lane l32 handles 4 halves
// ---------------------------------------------------------------------------

__device__ __forceinline__ void h4_accum(const float2 raw, float4& a) {
    union { float2 f2; __half2 h2[2]; } u;
    u.f2 = raw;
    float2 lo = __half22float2(u.h2[0]);
    float2 hi = __half22float2(u.h2[1]);
    a.x += lo.x; a.y += lo.y; a.z += hi.x; a.w += hi.y;
}

__device__ __forceinline__ float2 pack_h4(float4 v) {
    union { __half2 h2[2]; float2 f2; } u;
    u.h2[0] = __floats2half2_rn(v.x, v.y);
    u.h2[1] = __floats2half2_rn(v.z, v.w);
    return u.f2;
}

// ---------------------------------------------------------------------------
// small dense helpers (fp32, no LDS, W L1/L2-resident)
// ---------------------------------------------------------------------------

#define MM16_STEP(kk, comp)                                           \
    {                                                                 \
        float4 w0 = W4[(size_t)(k4 + kk) * 32 + tx * 2];              \
        float4 w1 = W4[(size_t)(k4 + kk) * 32 + tx * 2 + 1];          \
        acc[0] = fmaf(a.comp, w0.x, acc[0]);                          \
        acc[1] = fmaf(a.comp, w0.y, acc[1]);                          \
        acc[2] = fmaf(a.comp, w0.z, acc[2]);                          \
        acc[3] = fmaf(a.comp, w0.w, acc[3]);                          \
        acc[4] = fmaf(a.comp, w1.x, acc[4]);                          \
        acc[5] = fmaf(a.comp, w1.y, acc[5]);                          \
        acc[6] = fmaf(a.comp, w1.z, acc[6]);                          \
        acc[7] = fmaf(a.comp, w1.w, acc[7]);                          \
    }

__device__ __forceinline__ void mm_tile16(const float* __restrict__ A,
                                          const float* __restrict__ W,
                                          float* __restrict__ C, int r0, int t) {
    int tx = t & 15, ty = t >> 4;
    int r = r0 + ty;
    const float4* A4 = (const float4*)A;
    const float4* W4 = (const float4*)W;
    float acc[8] = {0.f, 0.f, 0.f, 0.f, 0.f, 0.f, 0.f, 0.f};
#pragma unroll 4
    for (int kb = 0; kb < 32; ++kb) {
        float4 a = A4[(size_t)r * 32 + kb];
        int k4 = kb * 4;
        MM16_STEP(0, x)
        MM16_STEP(1, y)
        MM16_STEP(2, z)
        MM16_STEP(3, w)
    }
    float4* cp = (float4*)&C[(size_t)r * D + tx * 8];
    float4 o0, o1;
    o0.x = acc[0]; o0.y = acc[1]; o0.z = acc[2]; o0.w = acc[3];
    o1.x = acc[4]; o1.y = acc[5]; o1.z = acc[6]; o1.w = acc[7];
    cp[0] = o0;
    cp[1] = o1;
}

__device__ __forceinline__ void vecmat128(const float* __restrict__ v,
                                          const float* __restrict__ W,
                                          float* __restrict__ outp, int t) {
    if (t < D) {
        float acc = 0.f;
#pragma unroll 8
        for (int k = 0; k < D; ++k) acc = fmaf(v[k], W[(size_t)k * D + t], acc);
        outp[t] = acc;
    }
}

// ---------------------------------------------------------------------------
// K1: hetero {src hist | dst hist | W01 = W0@W1 | bv01 = b0@W1 | zero flag}
// no global atomics anywhere
// ---------------------------------------------------------------------------

__global__ __launch_bounds__(256) void hist2_w_kernel(
        const int* __restrict__ src, const int* __restrict__ dst,
        unsigned int* __restrict__ Hsrc, unsigned int* __restrict__ Hdst,
        const float* __restrict__ W0, const float* __restrict__ W1,
        const float* __restrict__ b0, float* __restrict__ W01,
        float* __restrict__ bv01, int* __restrict__ flag) {
    __shared__ unsigned int hist[HWORDS];
    int t = threadIdx.x;
    if (blockIdx.x < 2 * HB) {
        int isDst = (blockIdx.x >= HB);
        int hb = isDst ? (blockIdx.x - HB) : blockIdx.x;
        const int* keys = isDst ? dst : src;
        unsigned int* Hout = isDst ? Hdst : Hsrc;
        for (int i = t; i < HWORDS; i += 256) hist[i] = 0;
        __syncthreads();
        int base = hb * EPB;
        int end = base + EPB;
        for (int e = base + t; e < end; e += 256) {
            int n = keys[e];
            atomicAdd(&hist[n >> 2], 1u << ((n & 3) * 8));
        }
        __syncthreads();
        unsigned int* outp = Hout + (size_t)hb * HWORDS;
        for (int i = t; i < HWORDS; i += 256) outp[i] = hist[i];
    } else if (blockIdx.x < 2 * HB + MMW_BLOCKS) {
        mm_tile16(W0, W1, W01, (blockIdx.x - 2 * HB) * 16, t);
    } else if (blockIdx.x == 2 * HB + MMW_BLOCKS) {
        vecmat128(b0, W1, bv01, t);
    } else {
        int n = (blockIdx.x - 2 * HB - MMW_BLOCKS - 1) * 256 + t;
        if (n < N_NODES) flag[n] = 0;
    }
}

// ---------------------------------------------------------------------------
// K2: hetero {src merge -> dinv_out |
//             dst merge -> boff,dinv_in + in-block scan -> row_off partial |
//             Wc = W01@W2 | bc1 = bv01@W2 | bc2 = b1@W2}
// ---------------------------------------------------------------------------

__global__ __launch_bounds__(256) void merge_w_kernel(
        const unsigned int* __restrict__ Hsrc, const unsigned int* __restrict__ Hdst,
        float* __restrict__ dinv_out, float* __restrict__ dinv_in,
        int* __restrict__ row_off, int* __restrict__ blocksums,
        unsigned char* __restrict__ boff,
        const float* __restrict__ W01, const float* __restrict__ W2,
        const float* __restrict__ bv01, const float* __restrict__ b1,
        float* __restrict__ Wc, float* __restrict__ bc1, float* __restrict__ bc2) {
    int t = threadIdx.x;
    if (blockIdx.x < SCAN_BLOCKS) {
        int n = blockIdx.x * 256 + t;
        if (n >= N_NODES) return;
        int w = n >> 2, sh = (n & 3) * 8;
        unsigned int s = 0;
#pragma unroll 8
        for (int b = 0; b < HB; ++b) s += (Hsrc[(size_t)b * HWORDS + w] >> sh) & 0xFFu;
        dinv_out[n] = (s > 0) ? 1.0f / sqrtf((float)s) : 0.0f;
    } else if (blockIdx.x < 2 * SCAN_BLOCKS) {
        int sb = blockIdx.x - SCAN_BLOCKS;
        int n = sb * 256 + t;
        unsigned int run = 0;
        if (n < N_NODES) {
            int w = n >> 2, sh = (n & 3) * 8;
            for (int b = 0; b < HB; ++b) {
                boff[(size_t)b * N_NODES + n] = (unsigned char)run;
                run += (Hdst[(size_t)b * HWORDS + w] >> sh) & 0xFFu;
            }
            dinv_in[n] = (run > 0) ? 1.0f / sqrtf((float)run) : 0.0f;
        }
        // in-block inclusive scan of counts -> row_off partial
        __shared__ int s_[256];
        s_[t] = (int)run;
        __syncthreads();
        for (int offs = 1; offs < 256; offs <<= 1) {
            int add = (t >= offs) ? s_[t - offs] : 0;
            __syncthreads();
            s_[t] += add;
            __syncthreads();
        }
        if (n < N_NODES) row_off[n + 1] = s_[t];
        if (t == 255) blocksums[sb] = s_[255];
    } else if (blockIdx.x < 2 * SCAN_BLOCKS + MMW_BLOCKS) {
        mm_tile16(W01, W2, Wc, (blockIdx.x - 2 * SCAN_BLOCKS) * 16, t);
    } else if (blockIdx.x == 2 * SCAN_BLOCKS + MMW_BLOCKS) {
        vecmat128(bv01, W2, bc1, t);
    } else {
        vecmat128(b1, W2, bc2, t);
    }
}

// ---------------------------------------------------------------------------
// K3: hetero {finish row_off scan (inline top-level prefix) | dinv_io}
// ---------------------------------------------------------------------------

__global__ __launch_bounds__(256) void scanfin_dio_kernel(
        int* __restrict__ row_off, const int* __restrict__ blocksums,
        const float* __restrict__ dinv_out, const float* __restrict__ dinv_in,
        float* __restrict__ dinv_io) {
    int t = threadIdx.x;
    if (blockIdx.x < SCAN_BLOCKS) {
        __shared__ int bs[256];
        __shared__ int off_s;
        bs[t] = (t < SCAN_BLOCKS) ? blocksums[t] : 0;
        __syncthreads();
        if (t == 0) {
            int s = 0;
            for (int b = 0; b < (int)blockIdx.x; ++b) s += bs[b];
            off_s = s;
        }
        __syncthreads();
        int i = blockIdx.x * 256 + t;
        if (i < N_NODES) row_off[i + 1] += off_s;
        if (i == 0) row_off[0] = 0;
    } else {
        int n = (blockIdx.x - SCAN_BLOCKS) * 256 + t;
        if (n < N_NODES) dinv_io[n] = dinv_out[n] * dinv_in[n];
    }
}

// ---------------------------------------------------------------------------
// K4: hetero {fill CSR via LDS local positions | prescale p0h = half(Dout*feat)}
// ---------------------------------------------------------------------------

__global__ __launch_bounds__(256) void fill_prescale_kernel(
        const int* __restrict__ src, const int* __restrict__ dst,
        const int* __restrict__ row_off, const unsigned char* __restrict__ boff,
        int* __restrict__ csr_src,
        const float4* __restrict__ feat4, const float* __restrict__ dinv_out,
        float4* __restrict__ p0h4) {
    __shared__ unsigned int lcnt[HWORDS];
    int t = threadIdx.x;
    if (blockIdx.x < HB) {
        for (int i = t; i < HWORDS; i += 256) lcnt[i] = 0;
        __syncthreads();
        int b = blockIdx.x;
        int base = b * EPB;
        int end = base + EPB;
        const unsigned char* bo = boff + (size_t)b * N_NODES;
        for (int e = base + t; e < end; e += 256) {
            int d = dst[e];
            int sh = (d & 3) * 8;
            unsigned int old = atomicAdd(&lcnt[d >> 2], 1u << sh);
            int local = (int)((old >> sh) & 0xFFu);
            csr_src[row_off[d] + (int)bo[d] + local] = src[e];
        }
    } else {
        int i = (blockIdx.x - HB) * 256 + t;  // half8-chunk index (8 floats -> 8 halves)
        if (i < N_NODES * 16) {
            int n = i >> 4;
            float s = dinv_out[n];
            float4 va = feat4[(size_t)i * 2];
            float4 vb = feat4[(size_t)i * 2 + 1];
            union { __half2 h[4]; float4 f; } u;
            u.h[0] = __floats2half2_rn(va.x * s, va.y * s);
            u.h[1] = __floats2half2_rn(va.z * s, va.w * s);
            u.h[2] = __floats2half2_rn(vb.x * s, vb.y * s);
            u.h[3] = __floats2half2_rn(vb.z * s, vb.w * s);
            p0h4[i] = u.f;
        }
    }
}

// ---------------------------------------------------------------------------
// fp16-table pull-aggregation body (uniform-batch, 4-deep, optional scalar sums)
// tab rows: 128 halves (256 B); lane l32 covers halves [l32*4, l32*4+4)
// ---------------------------------------------------------------------------

__device__ __forceinline__ void agg_row_body_h(const float2* __restrict__ h2,
                                               const int* __restrict__ csr_src,
                                               const float* __restrict__ wtab1,
                                               const float* __restrict__ wtab2,
                                               int start, int end, int lane, int hw, int l32,
                                               float4& accOut, float& ws1, float& ws2) {
    float4 a0 = make_float4(0.f, 0.f, 0.f, 0.f);
    float4 a1 = a0, a2 = a0, a3 = a0;
    float w1a = 0.f, w2a = 0.f;
    for (int j0 = start; j0 < end; j0 += 64) {
        int jj = j0 + lane;
        int sv = (jj < end) ? csr_src[jj] : 0;
        int nj = min(64, end - j0);
        int i = 0;
        for (; i + 8 <= nj; i += 8) {
            int s0 = __shfl(sv, i + hw, 64);
            int s1 = __shfl(sv, i + 2 + hw, 64);
            int s2 = __shfl(sv, i + 4 + hw, 64);
            int s3 = __shfl(sv, i + 6 + hw, 64);
            float2 r0 = h2[(size_t)s0 * 32 + l32];
            float2 r1 = h2[(size_t)s1 * 32 + l32];
            float2 r2 = h2[(size_t)s2 * 32 + l32];
            float2 r3 = h2[(size_t)s3 * 32 + l32];
            if (wtab1) w1a += (wtab1[s0] + wtab1[s1]) + (wtab1[s2] + wtab1[s3]);
            if (wtab2) w2a += (wtab2[s0] + wtab2[s1]) + (wtab2[s2] + wtab2[s3]);
            h4_accum(r0, a0);
            h4_accum(r1, a1);
            h4_accum(r2, a2);
            h4_accum(r3, a3);
        }
        for (; i < nj; i += 2) {
            int idx = i + hw;
            int s = __shfl(sv, idx, 64);
            if (idx < nj) {
                float2 r0 = h2[(size_t)s * 32 + l32];
                if (wtab1) w1a += wtab1[s];
                if (wtab2) w2a += wtab2[s];
                h4_accum(r0, a0);
            }
        }
    }
    accOut.x = (a0.x + a1.x) + (a2.x + a3.x);
    accOut.y = (a0.y + a1.y) + (a2.y + a3.y);
    accOut.z = (a0.z + a1.z) + (a2.z + a3.z);
    accOut.w = (a0.w + a1.w) + (a2.w + a3.w);
    ws1 = w1a;
    ws2 = w2a;
}

// ---------------------------------------------------------------------------
// K5: {agg1: p1h = half(Dio A p0h) | flag label-edge sources}
// ---------------------------------------------------------------------------

__global__ __launch_bounds__(256) void agg1_flag_kernel(
        const float2* __restrict__ p0h, const int* __restrict__ csr_src,
        const int* __restrict__ row_off, const float* __restrict__ dinv_io,
        float2* __restrict__ p1h,
        const int* __restrict__ labels, int* __restrict__ flag) {
    int t = threadIdx.x;
    if (blockIdx.x < AGG_BLOCKS) {
        int wave = t >> 6;
        int lane = t & 63;
        int hw = lane >> 5, l32 = lane & 31;
        int n = blockIdx.x * 4 + wave;
        if (n >= N_NODES) return;
        float4 acc;
        float d1, d2;
        agg_row_body_h(p0h, csr_src, nullptr, nullptr,
                       row_off[n], row_off[n + 1], lane, hw, l32, acc, d1, d2);
        acc.x += __shfl_xor(acc.x, 32, 64);
        acc.y += __shfl_xor(acc.y, 32, 64);
        acc.z += __shfl_xor(acc.z, 32, 64);
        acc.w += __shfl_xor(acc.w, 32, 64);
        if (hw == 0) {
            float wi = dinv_io[n];
            float4 r;
            r.x = acc.x * wi; r.y = acc.y * wi; r.z = acc.z * wi; r.w = acc.w * wi;
            p1h[(size_t)n * 32 + l32] = pack_h4(r);
        }
    } else {
        int i = (blockIdx.x - AGG_BLOCKS) * 256 + t;
        if (i < N_LABELS) {
            int n = labels[i];
            int a = row_off[n], bnd = row_off[n + 1];
            for (int j = a; j < bnd; ++j) flag[csr_src[j]] = 1;
        }
    }
}

// ---------------------------------------------------------------------------
// K6: agg2 on flagged rows with fused u1s: p2h = half(Dio A p1h); u1s = Dio*sum dout[s]
// ---------------------------------------------------------------------------

__global__ __launch_bounds__(256) void agg2_kernel(
        const float2* __restrict__ p1h, const int* __restrict__ csr_src,
        const int* __restrict__ row_off, const float* __restrict__ dinv_io,
        const int* __restrict__ flag, float2* __restrict__ p2h,
        const float* __restrict__ dinv_out, float* __restrict__ u1s) {
    int t = threadIdx.x;
    int wave = t >> 6;
    int lane = t & 63;
    int hw = lane >> 5, l32 = lane & 31;
    int n = blockIdx.x * 4 + wave;
    if (n >= N_NODES) return;
    if (!flag[n]) return;
    float4 acc;
    float ws1, d2;
    agg_row_body_h(p1h, csr_src, dinv_out, nullptr,
                   row_off[n], row_off[n + 1], lane, hw, l32, acc, ws1, d2);
    acc.x += __shfl_xor(acc.x, 32, 64);
    acc.y += __shfl_xor(acc.y, 32, 64);
    acc.z += __shfl_xor(acc.z, 32, 64);
    acc.w += __shfl_xor(acc.w, 32, 64);
    ws1 += __shfl_xor(ws1, 32, 64);
    float wi = dinv_io[n];
    if (lane == 0) u1s[n] = wi * ws1;
    if (hw == 0) {
        float4 r;
        r.x = acc.x * wi; r.y = acc.y * wi; r.z = acc.z * wi; r.w = acc.w * wi;
        p2h[(size_t)n * 32 + l32] = pack_h4(r);
    }
}

// ---------------------------------------------------------------------------
// K7: fused {label agg (+ scalar sums for u1,u2) -> LDS | 16-row matmul vs Wc}
// ---------------------------------------------------------------------------

__global__ __launch_bounds__(256) void agg_label_matmul_kernel(
        const float2* __restrict__ p2h, const int* __restrict__ csr_src,
        const int* __restrict__ row_off, const float* __restrict__ dinv_in,
        const int* __restrict__ labels,
        const float* __restrict__ dinv_out, const float* __restrict__ u1s,
        const float* __restrict__ Wc, const float* __restrict__ bc1,
        const float* __restrict__ bc2, const float* __restrict__ b2,
        float* __restrict__ outbuf) {
    __shared__ float tl[16][D];
    __shared__ float sb[16][2];
    int t = threadIdx.x;
    int wave = t >> 6, lane = t & 63;
    int hw = lane >> 5, l32 = lane & 31;
    int rbase = blockIdx.x * 16;
#pragma unroll
    for (int rr = 0; rr < 4; ++rr) {
        int row = rbase + wave * 4 + rr;
        int n = labels[row];
        float4 acc;
        float ws1, ws2;
        agg_row_body_h(p2h, csr_src, dinv_out, u1s,
                       row_off[n], row_off[n + 1], lane, hw, l32, acc, ws1, ws2);
        acc.x += __shfl_xor(acc.x, 32, 64);
        acc.y += __shfl_xor(acc.y, 32, 64);
        acc.z += __shfl_xor(acc.z, 32, 64);
        acc.w += __shfl_xor(acc.w, 32, 64);
        ws1 += __shfl_xor(ws1, 32, 64);
        ws2 += __shfl_xor(ws2, 32, 64);
        float wi = dinv_in[n];
        if (lane == 0) {
            sb[wave * 4 + rr][0] = wi * ws1;  // u1 at this label row
            sb[wave * 4 + rr][1] = wi * ws2;  // u2 at this label row
        }
        if (hw == 0) {
            float4 r;
            r.x = acc.x * wi; r.y = acc.y * wi; r.z = acc.z * wi; r.w = acc.w * wi;
            ((float4*)&tl[wave * 4 + rr][0])[l32] = r;
        }
    }
    __syncthreads();

    int tx = t & 15, ty = t >> 4;
    int r = rbase + ty;
    float s1 = sb[ty][0], s2 = sb[ty][1];
    float4 c10 = ((const float4*)bc1)[tx * 2];
    float4 c11 = ((const float4*)bc1)[tx * 2 + 1];
    float4 c20 = ((const float4*)bc2)[tx * 2];
    float4 c21 = ((const float4*)bc2)[tx * 2 + 1];
    float4 bz0 = ((const float4*)b2)[tx * 2];
    float4 bz1 = ((const float4*)b2)[tx * 2 + 1];

    float acc[8];
    acc[0] = fmaf(s2, c10.x, fmaf(s1, c20.x, bz0.x));
    acc[1] = fmaf(s2, c10.y, fmaf(s1, c20.y, bz0.y));
    acc[2] = fmaf(s2, c10.z, fmaf(s1, c20.z, bz0.z));
    acc[3] = fmaf(s2, c10.w, fmaf(s1, c20.w, bz0.w));
    acc[4] = fmaf(s2, c11.x, fmaf(s1, c21.x, bz1.x));
    acc[5] = fmaf(s2, c11.y, fmaf(s1, c21.y, bz1.y));
    acc[6] = fmaf(s2, c11.z, fmaf(s1, c21.z, bz1.z));
    acc[7] = fmaf(s2, c11.w, fmaf(s1, c21.w, bz1.w));

    const float4* W4 = (const float4*)Wc;
#pragma unroll 4
    for (int kb = 0; kb < 32; ++kb) {
        float4 a = ((const float4*)&tl[ty][0])[kb];
        int k4 = kb * 4;
        MM16_STEP(0, x)
        MM16_STEP(1, y)
        MM16_STEP(2, z)
        MM16_STEP(3, w)
    }

    float4 o0, o1;
    o0.x = acc[0]; o0.y = acc[1]; o0.z = acc[2]; o0.w = acc[3];
    o1.x = acc[4]; o1.y = acc[5]; o1.z = acc[6]; o1.w = acc[7];
    float4* op = (float4*)&outbuf[(size_t)r * D + tx * 8];
    op[0] = o0;
    op[1] = o1;
}

// ---------------------------------------------------------------------------

extern "C" void kernel_launch(void* const* d_in, const int* in_sizes, int n_in,
                              void* d_out, int out_size, void* d_ws, size_t ws_size,
                              hipStream_t stream) {
    const int* labels = (const int*)d_in[0];
    const int* src    = (const int*)d_in[1];
    const int* dst    = (const int*)d_in[2];
    const float* feat = (const float*)d_in[3];
    const float* W0   = (const float*)d_in[4];
    const float* b0   = (const float*)d_in[5];
    const float* W1   = (const float*)d_in[6];
    const float* b1   = (const float*)d_in[7];
    const float* W2   = (const float*)d_in[8];
    const float* b2   = (const float*)d_in[9];
    float* out = (float*)d_out;

    char* ws = (char*)d_ws;
    size_t off = 0;
    auto alloc = [&](size_t bytes) -> void* {
        void* p = ws + off;
        off = (off + bytes + 255) & ~(size_t)255;
        return p;
    };
    int* row_off    = (int*)alloc((N_NODES + 1) * 4);
    int* blocksums  = (int*)alloc(256 * 4);
    int* csr_src    = (int*)alloc((size_t)N_EDGES * 4);
    int* flag       = (int*)alloc(N_NODES * 4);
    float* dinv_out = (float*)alloc(N_NODES * 4);
    float* dinv_in  = (float*)alloc(N_NODES * 4);
    float* dinv_io  = (float*)alloc(N_NODES * 4);
    float* u1s      = (float*)alloc(N_NODES * 4);
    float* W01      = (float*)alloc((size_t)D * D * 4);
    float* Wc       = (float*)alloc((size_t)D * D * 4);
    float* bv01     = (float*)alloc(D * 4);
    float* bc1      = (float*)alloc(D * 4);
    float* bc2      = (float*)alloc(D * 4);
    unsigned char* boff = (unsigned char*)alloc((size_t)HB * N_NODES);  // 12.8 MB
    float* BUF1 = (float*)alloc((size_t)N_NODES * D * 4);  // p0h | p2h
    float* BUF2 = (float*)alloc((size_t)N_NODES * D * 4);  // Hsrc+Hdst | p1h

    // aliases (stream-ordered lifetimes):
    unsigned int* Hsrc = (unsigned int*)BUF2;                       // dead after K2
    unsigned int* Hdst = (unsigned int*)BUF2 + (size_t)HB * HWORDS; // dead after K2
    float2* p0h = (float2*)BUF1;   // fp16 rows (256 B), written K4, read K5
    float2* p1h = (float2*)BUF2;   // written K5, read K6
    float2* p2h = (float2*)BUF1;   // p0h dead after K5

    // K1: src hist + dst hist + W01 + bv01 + zero flag
    hist2_w_kernel<<<2 * HB + MMW_BLOCKS + 1 + SCAN_BLOCKS, 256, 0, stream>>>(
        src, dst, Hsrc, Hdst, W0, W1, b0, W01, bv01, flag);
    // K2: merges (+dst in-block scan) + Wc + bc1 + bc2
    merge_w_kernel<<<2 * SCAN_BLOCKS + MMW_BLOCKS + 2, 256, 0, stream>>>(
        Hsrc, Hdst, dinv_out, dinv_in, row_off, blocksums, boff,
        W01, W2, bv01, b1, Wc, bc1, bc2);
    // K3: finish scan + dinv_io
    scanfin_dio_kernel<<<2 * SCAN_BLOCKS, 256, 0, stream>>>(
        row_off, blocksums, dinv_out, dinv_in, dinv_io);
    // K4: fill (LDS local positions) + prescale (fp16)
    fill_prescale_kernel<<<HB + PRESCALE_BLOCKS, 256, 0, stream>>>(
        src, dst, row_off, boff, csr_src, (const float4*)feat, dinv_out, (float4*)p0h);
    // K5: agg1 (fp16 tables) + flag
    agg1_flag_kernel<<<AGG_BLOCKS + FLAG_BLOCKS, 256, 0, stream>>>(
        p0h, csr_src, row_off, dinv_io, p1h, labels, flag);
    // K6: agg2 on flagged rows (fp16), fused u1s
    agg2_kernel<<<AGG_BLOCKS, 256, 0, stream>>>(
        p1h, csr_src, row_off, dinv_io, flag, p2h, dinv_out, u1s);
    // K7: fused label agg (+u1,u2 scalar sums) + final matmul
    agg_label_matmul_kernel<<<N_LABELS / 16, 256, 0, stream>>>(
        p2h, csr_src, row_off, dinv_in, labels, dinv_out, u1s, Wc, bc1, bc2, b2, out);
}

// Round 15
// 153.277 us; speedup vs baseline: 1.5518x; 1.0104x over previous
//
#include <hip/hip_runtime.h>
#include <hip/hip_fp16.h>

#define N_NODES 50000
#define N_EDGES 800000
#define D 128
#define N_LABELS 4096
#define HB 128           // histogram blocks (6250 edges each, exact)
#define HWORDS 12500     // 50000/4 packed u8 counters per block (50 KB LDS)
#define EPB (N_EDGES / HB)     // 6250 edges per hist/fill block
#define PRESCALE_BLOCKS 3125   // N_NODES*16 half8-chunks / 256
#define AGG_BLOCKS 12500       // 4 nodes per block
#define FLAG_BLOCKS 16         // 4096 labels / 256
#define SCAN_BLOCKS 196
#define MMW_BLOCKS 8           // 128x128 matmul, 16 rows/block

// ---------------------------------------------------------------------------
// fp16 helpers: tables store 128 halves/row (256 B); lane l32 handles 4 halves
// ---------------------------------------------------------------------------

__device__ __forceinline__ void h4_accum(const float2 raw, float4& a) {
    union { float2 f2; __half2 h2[2]; } u;
    u.f2 = raw;
    float2 lo = __half22float2(u.h2[0]);
    float2 hi = __half22float2(u.h2[1]);
    a.x += lo.x; a.y += lo.y; a.z += hi.x; a.w += hi.y;
}

__device__ __forceinline__ float2 pack_h4(float4 v) {
    union { __half2 h2[2]; float2 f2; } u;
    u.h2[0] = __floats2half2_rn(v.x, v.y);
    u.h2[1] = __floats2half2_rn(v.z, v.w);
    return u.f2;
}

// ---------------------------------------------------------------------------
// small dense helpers (fp32, no LDS, W L1/L2-resident)
// ---------------------------------------------------------------------------

#define MM16_STEP(kk, comp)                                           \
    {                                                                 \
        float4 w0 = W4[(size_t)(k4 + kk) * 32 + tx * 2];              \
        float4 w1 = W4[(size_t)(k4 + kk) * 32 + tx * 2 + 1];          \
        acc[0] = fmaf(a.comp, w0.x, acc[0]);                          \
        acc[1] = fmaf(a.comp, w0.y, acc[1]);                          \
        acc[2] = fmaf(a.comp, w0.z, acc[2]);                          \
        acc[3] = fmaf(a.comp, w0.w, acc[3]);                          \
        acc[4] = fmaf(a.comp, w1.x, acc[4]);                          \
        acc[5] = fmaf(a.comp, w1.y, acc[5]);                          \
        acc[6] = fmaf(a.comp, w1.z, acc[6]);                          \
        acc[7] = fmaf(a.comp, w1.w, acc[7]);                          \
    }

__device__ __forceinline__ void mm_tile16(const float* __restrict__ A,
                                          const float* __restrict__ W,
                                          float* __restrict__ C, int r0, int t) {
    int tx = t & 15, ty = t >> 4;
    int r = r0 + ty;
    const float4* A4 = (const float4*)A;
    const float4* W4 = (const float4*)W;
    float acc[8] = {0.f, 0.f, 0.f, 0.f, 0.f, 0.f, 0.f, 0.f};
#pragma unroll 4
    for (int kb = 0; kb < 32; ++kb) {
        float4 a = A4[(size_t)r * 32 + kb];
        int k4 = kb * 4;
        MM16_STEP(0, x)
        MM16_STEP(1, y)
        MM16_STEP(2, z)
        MM16_STEP(3, w)
    }
    float4* cp = (float4*)&C[(size_t)r * D + tx * 8];
    float4 o0, o1;
    o0.x = acc[0]; o0.y = acc[1]; o0.z = acc[2]; o0.w = acc[3];
    o1.x = acc[4]; o1.y = acc[5]; o1.z = acc[6]; o1.w = acc[7];
    cp[0] = o0;
    cp[1] = o1;
}

__device__ __forceinline__ void vecmat128(const float* __restrict__ v,
                                          const float* __restrict__ W,
                                          float* __restrict__ outp, int t) {
    if (t < D) {
        float acc = 0.f;
#pragma unroll 8
        for (int k = 0; k < D; ++k) acc = fmaf(v[k], W[(size_t)k * D + t], acc);
        outp[t] = acc;
    }
}

// ---------------------------------------------------------------------------
// K1: hetero {src hist | dst hist | W01 = W0@W1 | bv01 = b0@W1 | zero flag}
// no global atomics anywhere
// ---------------------------------------------------------------------------

__global__ __launch_bounds__(256) void hist2_w_kernel(
        const int* __restrict__ src, const int* __restrict__ dst,
        unsigned int* __restrict__ Hsrc, unsigned int* __restrict__ Hdst,
        const float* __restrict__ W0, const float* __restrict__ W1,
        const float* __restrict__ b0, float* __restrict__ W01,
        float* __restrict__ bv01, int* __restrict__ flag) {
    __shared__ unsigned int hist[HWORDS];
    int t = threadIdx.x;
    if (blockIdx.x < 2 * HB) {
        int isDst = (blockIdx.x >= HB);
        int hb = isDst ? (blockIdx.x - HB) : blockIdx.x;
        const int* keys = isDst ? dst : src;
        unsigned int* Hout = isDst ? Hdst : Hsrc;
        for (int i = t; i < HWORDS; i += 256) hist[i] = 0;
        __syncthreads();
        int base = hb * EPB;
        int end = base + EPB;
        for (int e = base + t; e < end; e += 256) {
            int n = keys[e];
            atomicAdd(&hist[n >> 2], 1u << ((n & 3) * 8));
        }
        __syncthreads();
        unsigned int* outp = Hout + (size_t)hb * HWORDS;
        for (int i = t; i < HWORDS; i += 256) outp[i] = hist[i];
    } else if (blockIdx.x < 2 * HB + MMW_BLOCKS) {
        mm_tile16(W0, W1, W01, (blockIdx.x - 2 * HB) * 16, t);
    } else if (blockIdx.x == 2 * HB + MMW_BLOCKS) {
        vecmat128(b0, W1, bv01, t);
    } else {
        int n = (blockIdx.x - 2 * HB - MMW_BLOCKS - 1) * 256 + t;
        if (n < N_NODES) flag[n] = 0;
    }
}

// ---------------------------------------------------------------------------
// K2: hetero {src merge -> dinv_out |
//             dst merge -> boff,dinv_in + in-block scan -> row_off partial |
//             Wc = W01@W2 | bc1 = bv01@W2 | bc2 = b1@W2}
// ---------------------------------------------------------------------------

__global__ __launch_bounds__(256) void merge_w_kernel(
        const unsigned int* __restrict__ Hsrc, const unsigned int* __restrict__ Hdst,
        float* __restrict__ dinv_out, float* __restrict__ dinv_in,
        int* __restrict__ row_off, int* __restrict__ blocksums,
        unsigned char* __restrict__ boff,
        const float* __restrict__ W01, const float* __restrict__ W2,
        const float* __restrict__ bv01, const float* __restrict__ b1,
        float* __restrict__ Wc, float* __restrict__ bc1, float* __restrict__ bc2) {
    int t = threadIdx.x;
    if (blockIdx.x < SCAN_BLOCKS) {
        int n = blockIdx.x * 256 + t;
        if (n >= N_NODES) return;
        int w = n >> 2, sh = (n & 3) * 8;
        unsigned int s = 0;
#pragma unroll 8
        for (int b = 0; b < HB; ++b) s += (Hsrc[(size_t)b * HWORDS + w] >> sh) & 0xFFu;
        dinv_out[n] = (s > 0) ? 1.0f / sqrtf((float)s) : 0.0f;
    } else if (blockIdx.x < 2 * SCAN_BLOCKS) {
        int sb = blockIdx.x - SCAN_BLOCKS;
        int n = sb * 256 + t;
        unsigned int run = 0;
        if (n < N_NODES) {
            int w = n >> 2, sh = (n & 3) * 8;
            for (int b = 0; b < HB; ++b) {
                boff[(size_t)b * N_NODES + n] = (unsigned char)run;
                run += (Hdst[(size_t)b * HWORDS + w] >> sh) & 0xFFu;
            }
            dinv_in[n] = (run > 0) ? 1.0f / sqrtf((float)run) : 0.0f;
        }
        // in-block inclusive scan of counts -> row_off partial
        __shared__ int s_[256];
        s_[t] = (int)run;
        __syncthreads();
        for (int offs = 1; offs < 256; offs <<= 1) {
            int add = (t >= offs) ? s_[t - offs] : 0;
            __syncthreads();
            s_[t] += add;
            __syncthreads();
        }
        if (n < N_NODES) row_off[n + 1] = s_[t];
        if (t == 255) blocksums[sb] = s_[255];
    } else if (blockIdx.x < 2 * SCAN_BLOCKS + MMW_BLOCKS) {
        mm_tile16(W01, W2, Wc, (blockIdx.x - 2 * SCAN_BLOCKS) * 16, t);
    } else if (blockIdx.x == 2 * SCAN_BLOCKS + MMW_BLOCKS) {
        vecmat128(bv01, W2, bc1, t);
    } else {
        vecmat128(b1, W2, bc2, t);
    }
}

// ---------------------------------------------------------------------------
// K3: hetero {finish row_off scan (inline top-level prefix) | dinv_io}
// ---------------------------------------------------------------------------

__global__ __launch_bounds__(256) void scanfin_dio_kernel(
        int* __restrict__ row_off, const int* __restrict__ blocksums,
        const float* __restrict__ dinv_out, const float* __restrict__ dinv_in,
        float* __restrict__ dinv_io) {
    int t = threadIdx.x;
    if (blockIdx.x < SCAN_BLOCKS) {
        __shared__ int bs[256];
        __shared__ int off_s;
        bs[t] = (t < SCAN_BLOCKS) ? blocksums[t] : 0;
        __syncthreads();
        if (t == 0) {
            int s = 0;
            for (int b = 0; b < (int)blockIdx.x; ++b) s += bs[b];
            off_s = s;
        }
        __syncthreads();
        int i = blockIdx.x * 256 + t;
        if (i < N_NODES) row_off[i + 1] += off_s;
        if (i == 0) row_off[0] = 0;
    } else {
        int n = (blockIdx.x - SCAN_BLOCKS) * 256 + t;
        if (n < N_NODES) dinv_io[n] = dinv_out[n] * dinv_in[n];
    }
}

// ---------------------------------------------------------------------------
// K4: hetero {fill CSR (u16) via LDS local positions | prescale p0h = half(Dout*feat)}
// ---------------------------------------------------------------------------

__global__ __launch_bounds__(256) void fill_prescale_kernel(
        const int* __restrict__ src, const int* __restrict__ dst,
        const int* __restrict__ row_off, const unsigned char* __restrict__ boff,
        unsigned short* __restrict__ csr_src,
        const float4* __restrict__ feat4, const float* __restrict__ dinv_out,
        float4* __restrict__ p0h4) {
    __shared__ unsigned int lcnt[HWORDS];
    int t = threadIdx.x;
    if (blockIdx.x < HB) {
        for (int i = t; i < HWORDS; i += 256) lcnt[i] = 0;
        __syncthreads();
        int b = blockIdx.x;
        int base = b * EPB;
        int end = base + EPB;
        const unsigned char* bo = boff + (size_t)b * N_NODES;
        for (int e = base + t; e < end; e += 256) {
            int d = dst[e];
            int sh = (d & 3) * 8;
            unsigned int old = atomicAdd(&lcnt[d >> 2], 1u << sh);
            int local = (int)((old >> sh) & 0xFFu);
            csr_src[row_off[d] + (int)bo[d] + local] = (unsigned short)src[e];
        }
    } else {
        int i = (blockIdx.x - HB) * 256 + t;  // half8-chunk index (8 floats -> 8 halves)
        if (i < N_NODES * 16) {
            int n = i >> 4;
            float s = dinv_out[n];
            float4 va = feat4[(size_t)i * 2];
            float4 vb = feat4[(size_t)i * 2 + 1];
            union { __half2 h[4]; float4 f; } u;
            u.h[0] = __floats2half2_rn(va.x * s, va.y * s);
            u.h[1] = __floats2half2_rn(va.z * s, va.w * s);
            u.h[2] = __floats2half2_rn(vb.x * s, vb.y * s);
            u.h[3] = __floats2half2_rn(vb.z * s, vb.w * s);
            p0h4[i] = u.f;
        }
    }
}

// ---------------------------------------------------------------------------
// fp16-table pull-aggregation body (uniform-batch, 4-deep, optional scalar sums)
// tab rows: 128 halves (256 B); lane l32 covers halves [l32*4, l32*4+4)
// csr entries are u16 node ids
// ---------------------------------------------------------------------------

__device__ __forceinline__ void agg_row_body_h(const float2* __restrict__ h2,
                                               const unsigned short* __restrict__ csr_src,
                                               const float* __restrict__ wtab1,
                                               const float* __restrict__ wtab2,
                                               int start, int end, int lane, int hw, int l32,
                                               float4& accOut, float& ws1, float& ws2) {
    float4 a0 = make_float4(0.f, 0.f, 0.f, 0.f);
    float4 a1 = a0, a2 = a0, a3 = a0;
    float w1a = 0.f, w2a = 0.f;
    for (int j0 = start; j0 < end; j0 += 64) {
        int jj = j0 + lane;
        int sv = (jj < end) ? (int)csr_src[jj] : 0;
        int nj = min(64, end - j0);
        int i = 0;
        for (; i + 8 <= nj; i += 8) {
            int s0 = __shfl(sv, i + hw, 64);
            int s1 = __shfl(sv, i + 2 + hw, 64);
            int s2 = __shfl(sv, i + 4 + hw, 64);
            int s3 = __shfl(sv, i + 6 + hw, 64);
            float2 r0 = h2[(size_t)s0 * 32 + l32];
            float2 r1 = h2[(size_t)s1 * 32 + l32];
            float2 r2 = h2[(size_t)s2 * 32 + l32];
            float2 r3 = h2[(size_t)s3 * 32 + l32];
            if (wtab1) w1a += (wtab1[s0] + wtab1[s1]) + (wtab1[s2] + wtab1[s3]);
            if (wtab2) w2a += (wtab2[s0] + wtab2[s1]) + (wtab2[s2] + wtab2[s3]);
            h4_accum(r0, a0);
            h4_accum(r1, a1);
            h4_accum(r2, a2);
            h4_accum(r3, a3);
        }
        for (; i < nj; i += 2) {
            int idx = i + hw;
            int s = __shfl(sv, idx, 64);
            if (idx < nj) {
                float2 r0 = h2[(size_t)s * 32 + l32];
                if (wtab1) w1a += wtab1[s];
                if (wtab2) w2a += wtab2[s];
                h4_accum(r0, a0);
            }
        }
    }
    accOut.x = (a0.x + a1.x) + (a2.x + a3.x);
    accOut.y = (a0.y + a1.y) + (a2.y + a3.y);
    accOut.z = (a0.z + a1.z) + (a2.z + a3.z);
    accOut.w = (a0.w + a1.w) + (a2.w + a3.w);
    ws1 = w1a;
    ws2 = w2a;
}

// ---------------------------------------------------------------------------
// K5: {agg1: p1h = half(Dio A p0h) | flag label-edge sources}
// ---------------------------------------------------------------------------

__global__ __launch_bounds__(256) void agg1_flag_kernel(
        const float2* __restrict__ p0h, const unsigned short* __restrict__ csr_src,
        const int* __restrict__ row_off, const float* __restrict__ dinv_io,
        float2* __restrict__ p1h,
        const int* __restrict__ labels, int* __restrict__ flag) {
    int t = threadIdx.x;
    if (blockIdx.x < AGG_BLOCKS) {
        int wave = t >> 6;
        int lane = t & 63;
        int hw = lane >> 5, l32 = lane & 31;
        int n = blockIdx.x * 4 + wave;
        if (n >= N_NODES) return;
        float4 acc;
        float d1, d2;
        agg_row_body_h(p0h, csr_src, nullptr, nullptr,
                       row_off[n], row_off[n + 1], lane, hw, l32, acc, d1, d2);
        acc.x += __shfl_xor(acc.x, 32, 64);
        acc.y += __shfl_xor(acc.y, 32, 64);
        acc.z += __shfl_xor(acc.z, 32, 64);
        acc.w += __shfl_xor(acc.w, 32, 64);
        if (hw == 0) {
            float wi = dinv_io[n];
            float4 r;
            r.x = acc.x * wi; r.y = acc.y * wi; r.z = acc.z * wi; r.w = acc.w * wi;
            p1h[(size_t)n * 32 + l32] = pack_h4(r);
        }
    } else {
        int i = (blockIdx.x - AGG_BLOCKS) * 256 + t;
        if (i < N_LABELS) {
            int n = labels[i];
            int a = row_off[n], bnd = row_off[n + 1];
            for (int j = a; j < bnd; ++j) flag[csr_src[j]] = 1;
        }
    }
}

// ---------------------------------------------------------------------------
// K6: agg2 on flagged rows with fused u1s: p2h = half(Dio A p1h); u1s = Dio*sum dout[s]
// ---------------------------------------------------------------------------

__global__ __launch_bounds__(256) void agg2_kernel(
        const float2* __restrict__ p1h, const unsigned short* __restrict__ csr_src,
        const int* __restrict__ row_off, const float* __restrict__ dinv_io,
        const int* __restrict__ flag, float2* __restrict__ p2h,
        const float* __restrict__ dinv_out, float* __restrict__ u1s) {
    int t = threadIdx.x;
    int wave = t >> 6;
    int lane = t & 63;
    int hw = lane >> 5, l32 = lane & 31;
    int n = blockIdx.x * 4 + wave;
    if (n >= N_NODES) return;
    if (!flag[n]) return;
    float4 acc;
    float ws1, d2;
    agg_row_body_h(p1h, csr_src, dinv_out, nullptr,
                   row_off[n], row_off[n + 1], lane, hw, l32, acc, ws1, d2);
    acc.x += __shfl_xor(acc.x, 32, 64);
    acc.y += __shfl_xor(acc.y, 32, 64);
    acc.z += __shfl_xor(acc.z, 32, 64);
    acc.w += __shfl_xor(acc.w, 32, 64);
    ws1 += __shfl_xor(ws1, 32, 64);
    float wi = dinv_io[n];
    if (lane == 0) u1s[n] = wi * ws1;
    if (hw == 0) {
        float4 r;
        r.x = acc.x * wi; r.y = acc.y * wi; r.z = acc.z * wi; r.w = acc.w * wi;
        p2h[(size_t)n * 32 + l32] = pack_h4(r);
    }
}

// ---------------------------------------------------------------------------
// K7: fused {label agg (+ scalar sums for u1,u2) -> LDS | 16-row matmul vs Wc}
// ---------------------------------------------------------------------------

__global__ __launch_bounds__(256) void agg_label_matmul_kernel(
        const float2* __restrict__ p2h, const unsigned short* __restrict__ csr_src,
        const int* __restrict__ row_off, const float* __restrict__ dinv_in,
        const int* __restrict__ labels,
        const float* __restrict__ dinv_out, const float* __restrict__ u1s,
        const float* __restrict__ Wc, const float* __restrict__ bc1,
        const float* __restrict__ bc2, const float* __restrict__ b2,
        float* __restrict__ outbuf) {
    __shared__ float tl[16][D];
    __shared__ float sb[16][2];
    int t = threadIdx.x;
    int wave = t >> 6, lane = t & 63;
    int hw = lane >> 5, l32 = lane & 31;
    int rbase = blockIdx.x * 16;
#pragma unroll
    for (int rr = 0; rr < 4; ++rr) {
        int row = rbase + wave * 4 + rr;
        int n = labels[row];
        float4 acc;
        float ws1, ws2;
        agg_row_body_h(p2h, csr_src, dinv_out, u1s,
                       row_off[n], row_off[n + 1], lane, hw, l32, acc, ws1, ws2);
        acc.x += __shfl_xor(acc.x, 32, 64);
        acc.y += __shfl_xor(acc.y, 32, 64);
        acc.z += __shfl_xor(acc.z, 32, 64);
        acc.w += __shfl_xor(acc.w, 32, 64);
        ws1 += __shfl_xor(ws1, 32, 64);
        ws2 += __shfl_xor(ws2, 32, 64);
        float wi = dinv_in[n];
        if (lane == 0) {
            sb[wave * 4 + rr][0] = wi * ws1;  // u1 at this label row
            sb[wave * 4 + rr][1] = wi * ws2;  // u2 at this label row
        }
        if (hw == 0) {
            float4 r;
            r.x = acc.x * wi; r.y = acc.y * wi; r.z = acc.z * wi; r.w = acc.w * wi;
            ((float4*)&tl[wave * 4 + rr][0])[l32] = r;
        }
    }
    __syncthreads();

    int tx = t & 15, ty = t >> 4;
    int r = rbase + ty;
    float s1 = sb[ty][0], s2 = sb[ty][1];
    float4 c10 = ((const float4*)bc1)[tx * 2];
    float4 c11 = ((const float4*)bc1)[tx * 2 + 1];
    float4 c20 = ((const float4*)bc2)[tx * 2];
    float4 c21 = ((const float4*)bc2)[tx * 2 + 1];
    float4 bz0 = ((const float4*)b2)[tx * 2];
    float4 bz1 = ((const float4*)b2)[tx * 2 + 1];

    float acc[8];
    acc[0] = fmaf(s2, c10.x, fmaf(s1, c20.x, bz0.x));
    acc[1] = fmaf(s2, c10.y, fmaf(s1, c20.y, bz0.y));
    acc[2] = fmaf(s2, c10.z, fmaf(s1, c20.z, bz0.z));
    acc[3] = fmaf(s2, c10.w, fmaf(s1, c20.w, bz0.w));
    acc[4] = fmaf(s2, c11.x, fmaf(s1, c21.x, bz1.x));
    acc[5] = fmaf(s2, c11.y, fmaf(s1, c21.y, bz1.y));
    acc[6] = fmaf(s2, c11.z, fmaf(s1, c21.z, bz1.z));
    acc[7] = fmaf(s2, c11.w, fmaf(s1, c21.w, bz1.w));

    const float4* W4 = (const float4*)Wc;
#pragma unroll 4
    for (int kb = 0; kb < 32; ++kb) {
        float4 a = ((const float4*)&tl[ty][0])[kb];
        int k4 = kb * 4;
        MM16_STEP(0, x)
        MM16_STEP(1, y)
        MM16_STEP(2, z)
        MM16_STEP(3, w)
    }

    float4 o0, o1;
    o0.x = acc[0]; o0.y = acc[1]; o0.z = acc[2]; o0.w = acc[3];
    o1.x = acc[4]; o1.y = acc[5]; o1.z = acc[6]; o1.w = acc[7];
    float4* op = (float4*)&outbuf[(size_t)r * D + tx * 8];
    op[0] = o0;
    op[1] = o1;
}

// ---------------------------------------------------------------------------

extern "C" void kernel_launch(void* const* d_in, const int* in_sizes, int n_in,
                              void* d_out, int out_size, void* d_ws, size_t ws_size,
                              hipStream_t stream) {
    const int* labels = (const int*)d_in[0];
    const int* src    = (const int*)d_in[1];
    const int* dst    = (const int*)d_in[2];
    const float* feat = (const float*)d_in[3];
    const float* W0   = (const float*)d_in[4];
    const float* b0   = (const float*)d_in[5];
    const float* W1   = (const float*)d_in[6];
    const float* b1   = (const float*)d_in[7];
    const float* W2   = (const float*)d_in[8];
    const float* b2   = (const float*)d_in[9];
    float* out = (float*)d_out;

    char* ws = (char*)d_ws;
    size_t off = 0;
    auto alloc = [&](size_t bytes) -> void* {
        void* p = ws + off;
        off = (off + bytes + 255) & ~(size_t)255;
        return p;
    };
    int* row_off    = (int*)alloc((N_NODES + 1) * 4);
    int* blocksums  = (int*)alloc(256 * 4);
    unsigned short* csr_src = (unsigned short*)alloc((size_t)N_EDGES * 2);
    int* flag       = (int*)alloc(N_NODES * 4);
    float* dinv_out = (float*)alloc(N_NODES * 4);
    float* dinv_in  = (float*)alloc(N_NODES * 4);
    float* dinv_io  = (float*)alloc(N_NODES * 4);
    float* u1s      = (float*)alloc(N_NODES * 4);
    float* W01      = (float*)alloc((size_t)D * D * 4);
    float* Wc       = (float*)alloc((size_t)D * D * 4);
    float* bv01     = (float*)alloc(D * 4);
    float* bc1      = (float*)alloc(D * 4);
    float* bc2      = (float*)alloc(D * 4);
    unsigned char* boff = (unsigned char*)alloc((size_t)HB * N_NODES);  // 6.4 MB
    float* BUF1 = (float*)alloc((size_t)N_NODES * D * 4);  // p0h | p2h
    float* BUF2 = (float*)alloc((size_t)N_NODES * D * 4);  // Hsrc+Hdst | p1h

    // aliases (stream-ordered lifetimes):
    unsigned int* Hsrc = (unsigned int*)BUF2;                       // dead after K2
    unsigned int* Hdst = (unsigned int*)BUF2 + (size_t)HB * HWORDS; // dead after K2
    float2* p0h = (float2*)BUF1;   // fp16 rows (256 B), written K4, read K5
    float2* p1h = (float2*)BUF2;   // written K5, read K6
    float2* p2h = (float2*)BUF1;   // p0h dead after K5

    // K1: src hist + dst hist + W01 + bv01 + zero flag
    hist2_w_kernel<<<2 * HB + MMW_BLOCKS + 1 + SCAN_BLOCKS, 256, 0, stream>>>(
        src, dst, Hsrc, Hdst, W0, W1, b0, W01, bv01, flag);
    // K2: merges (+dst in-block scan) + Wc + bc1 + bc2
    merge_w_kernel<<<2 * SCAN_BLOCKS + MMW_BLOCKS + 2, 256, 0, stream>>>(
        Hsrc, Hdst, dinv_out, dinv_in, row_off, blocksums, boff,
        W01, W2, bv01, b1, Wc, bc1, bc2);
    // K3: finish scan + dinv_io
    scanfin_dio_kernel<<<2 * SCAN_BLOCKS, 256, 0, stream>>>(
        row_off, blocksums, dinv_out, dinv_in, dinv_io);
    // K4: fill (u16 csr, LDS local positions) + prescale (fp16)
    fill_prescale_kernel<<<HB + PRESCALE_BLOCKS, 256, 0, stream>>>(
        src, dst, row_off, boff, csr_src, (const float4*)feat, dinv_out, (float4*)p0h);
    // K5: agg1 (fp16 tables) + flag
    agg1_flag_kernel<<<AGG_BLOCKS + FLAG_BLOCKS, 256, 0, stream>>>(
        p0h, csr_src, row_off, dinv_io, p1h, labels, flag);
    // K6: agg2 on flagged rows (fp16), fused u1s
    agg2_kernel<<<AGG_BLOCKS, 256, 0, stream>>>(
        p1h, csr_src, row_off, dinv_io, flag, p2h, dinv_out, u1s);
    // K7: fused label agg (+u1,u2 scalar sums) + final matmul
    agg_label_matmul_kernel<<<N_LABELS / 16, 256, 0, stream>>>(
        p2h, csr_src, row_off, dinv_in, labels, dinv_out, u1s, Wc, bc1, bc2, b2, out);
}